// Round 18
// baseline (952.480 us; speedup 1.0000x reference)
//
#include <hip/hip_runtime.h>
#include <stdint.h>

typedef unsigned short u16;
using bf16x8 = __attribute__((ext_vector_type(8))) short;
using f32x4  = __attribute__((ext_vector_type(4))) float;

#define BATCH 2
#define SEQ   2048
#define TOK   (BATCH*SEQ)      // 4096 tokens
#define DM    1024
#define NLAY  4
#define DI    2048
#define DSTT  64               // state dim DS
#define NH    32               // heads
#define HP    64               // head dim P
#define KC    4                // conv kernel
#define CHK   64               // chunk len
#define NC    (SEQ/CHK)        // 32 chunks
#define DCONV (DI + 2*DSTT)    // 2176
#define DINR  (2*DI + 2*DSTT + NH) // 4256
#define DINP  4352             // padded to 128 multiple
#define HPB   4                // heads per ydiagm block

#define MFMA16 __builtin_amdgcn_mfma_f32_16x16x32_bf16

__device__ __forceinline__ float b2f(u16 u) {
    union { uint32_t i; float f; } v; v.i = ((uint32_t)u) << 16; return v.f;
}
__device__ __forceinline__ u16 f2b(float f) {
    union { float f; uint32_t i; } v; v.f = f;
    uint32_t x = v.i;
    uint32_t r = x + 0x7fffu + ((x >> 16) & 1u);
    return (u16)(r >> 16);
}
__device__ __forceinline__ void gload16(const u16* g, u16* l) {
    __builtin_amdgcn_global_load_lds(
        (const __attribute__((address_space(1))) void*)g,
        (__attribute__((address_space(3))) void*)l, 16, 0, 0);
}
// ---- 64x64 bf16 operand tiles: [2 k-tiles][64 rows][32 cols], gemm swizzle --
__device__ __forceinline__ int swzb(int byo) {
    return byo ^ (((byo >> 6) & 7) << 4);
}
__device__ __forceinline__ void st16(u16* base, int r, int k, u16 v) {
    int byo = ((k >> 5) << 12) | ((r * 32 + (k & 31)) << 1);
    *(u16*)((char*)base + swzb(byo)) = v;
}
__device__ __forceinline__ void st32(u16* base, int r, int k, uint32_t v) {
    int byo = ((k >> 5) << 12) | ((r * 32 + (k & 31)) << 1);   // k even
    *(uint32_t*)((char*)base + swzb(byo)) = v;
}
__device__ __forceinline__ bf16x8 ldfrag(const u16* base, int rbase, int kt, int lane) {
    int byo = (kt << 12) | (((rbase + (lane & 15)) * 32 + ((lane >> 4) << 3)) << 1);
    return *(const bf16x8*)((const char*)base + swzb(byo));
}

// ---------------- embedding gather: res[t,:] = emb[ids[t],:] (f32) ----------
__global__ __launch_bounds__(256) void embed_k(const int* __restrict__ ids,
                                               const float* __restrict__ emb,
                                               float* __restrict__ res) {
    int t = blockIdx.x, tid = threadIdx.x;
    int id = ids[t];
    const float* er = emb + (size_t)id * DM;
    int i0 = tid * 4;
    *(float4*)(res + (size_t)t * DM + i0) = *(const float4*)(er + i0);
}

// ---------------- layernorm over DM: src f32 -> dst (bf16 or f32) -----------
template <typename OutT>
__global__ __launch_bounds__(256) void ln_k(const float* __restrict__ src,
                                            const float* __restrict__ w,
                                            const float* __restrict__ bb,
                                            OutT* __restrict__ dst) {
    __shared__ float r1[4], r2[4];
    int t = blockIdx.x, tid = threadIdx.x;
    const float* x = src + (size_t)t * DM;
    int i0 = tid * 4;
    float4 v = *(const float4*)(x + i0);
    float s1 = v.x + v.y + v.z + v.w;
    float s2 = v.x * v.x + v.y * v.y + v.z * v.z + v.w * v.w;
#pragma unroll
    for (int off = 32; off; off >>= 1) {
        s1 += __shfl_down(s1, off);
        s2 += __shfl_down(s2, off);
    }
    if ((tid & 63) == 0) { r1[tid >> 6] = s1; r2[tid >> 6] = s2; }
    __syncthreads();
    float S1 = r1[0] + r1[1] + r1[2] + r1[3];
    float S2 = r2[0] + r2[1] + r2[2] + r2[3];
    float mean = S1 * (1.f / DM);
    float var = S2 * (1.f / DM) - mean * mean;
    float inv = rsqrtf(var + 1e-5f);
    float4 wv = *(const float4*)(w + i0);
    float4 bv = *(const float4*)(bb + i0);
    OutT* d = dst + (size_t)t * DM + i0;
    float o0 = (v.x - mean) * inv * wv.x + bv.x;
    float o1 = (v.y - mean) * inv * wv.y + bv.y;
    float o2 = (v.z - mean) * inv * wv.z + bv.z;
    float o3 = (v.w - mean) * inv * wv.w + bv.w;
    if constexpr (sizeof(OutT) == 2) {
        d[0] = f2b(o0); d[1] = f2b(o1); d[2] = f2b(o2); d[3] = f2b(o3);
    } else {
        float4 o; o.x = o0; o.y = o1; o.z = o2; o.w = o3;
        *(float4*)d = o;
    }
}

// ---------------- pad+convert in_w (4256x1024 f32) -> wpad (4352x1024 bf16) -
__global__ __launch_bounds__(256) void padw_k(const float* __restrict__ w,
                                              u16* __restrict__ wp) {
    int idx = (blockIdx.x * 256 + threadIdx.x) * 4;
    if (idx >= DINP * DM) return;
    if (idx < DINR * DM) {
        float4 v = *(const float4*)(w + idx);
        wp[idx + 0] = f2b(v.x); wp[idx + 1] = f2b(v.y);
        wp[idx + 2] = f2b(v.z); wp[idx + 3] = f2b(v.w);
    } else {
        wp[idx + 0] = 0; wp[idx + 1] = 0; wp[idx + 2] = 0; wp[idx + 3] = 0;
    }
}

// ---------------- generic f32 -> bf16 convert -------------------------------
__global__ __launch_bounds__(256) void cvt_k(const float* __restrict__ src,
                                             u16* __restrict__ dst, int n) {
    int idx = (blockIdx.x * 256 + threadIdx.x) * 4;
    if (idx >= n) return;
    float4 v = *(const float4*)(src + idx);
    dst[idx + 0] = f2b(v.x); dst[idx + 1] = f2b(v.y);
    dst[idx + 2] = f2b(v.z); dst[idx + 3] = f2b(v.w);
}

// ---------------- bf16 GEMM (m97 structure): C[m,n] = sum_k A[m,k]*B[n,k] ---
// Used only as gemm_k<0,1> (in-proj, bf16 LDS-coalesced store) — proven form.
template <int EPI, int KSPLIT>
__global__ __launch_bounds__(256) void gemm_k(const u16* __restrict__ A,
                                              const u16* __restrict__ Bw,
                                              u16* __restrict__ Cb,
                                              float* __restrict__ Cf,
                                              int N, int Kd, int ldc) {
    __shared__ u16 sm[8192];          // As = sm[0:4096], Bs = sm[4096:8192]
    u16* As = sm;
    u16* Bs = sm + 4096;
    const int tid = threadIdx.x;
    const int lane = tid & 63;
    const int w = tid >> 6;
    const int wm = w >> 1, wn = w & 1;
    const int nb = N >> 7;

    const int rowsPer = (gridDim.x / nb) >> 3;
    const int xcd = blockIdx.x & 7;
    const int local = blockIdx.x >> 3;
    const int bx = local / rowsPer;
    const int by = xcd * rowsPer + (local % rowsPer);
    const int row0 = by << 7, col0 = bx << 7;

    const int Kslice = Kd / KSPLIT;
    const int kbase = blockIdx.y * Kslice;

    const int srow = lane >> 2;
    const int skp  = (lane & 3) << 3;

    f32x4 zero = {0.f, 0.f, 0.f, 0.f};
    f32x4 acc[4][4];
#pragma unroll
    for (int i = 0; i < 4; i++)
#pragma unroll
        for (int j = 0; j < 4; j++) acc[i][j] = zero;

    const int tiles = Kslice >> 5;
    for (int kt = 0; kt < tiles; ++kt) {
        const int k0 = kbase + (kt << 5);
#pragma unroll
        for (int j = 0; j < 2; ++j) {
            int r = w * 32 + j * 16 + srow;
            gload16(A + (size_t)(row0 + r) * Kd + k0 + skp,
                    As + w * 1024 + j * 512);
            gload16(Bw + (size_t)(col0 + r) * Kd + k0 + skp,
                    Bs + w * 1024 + j * 512);
        }
        __syncthreads();
        bf16x8 af[4], bfr[4];
#pragma unroll
        for (int mi = 0; mi < 4; mi++) {
            int row = wm * 64 + mi * 16 + (lane & 15);
            af[mi] = *(const bf16x8*)(As + row * 32 + ((lane >> 4) << 3));
        }
#pragma unroll
        for (int ni = 0; ni < 4; ni++) {
            int row = wn * 64 + ni * 16 + (lane & 15);
            bfr[ni] = *(const bf16x8*)(Bs + row * 32 + ((lane >> 4) << 3));
        }
#pragma unroll
        for (int mi = 0; mi < 4; mi++)
#pragma unroll
            for (int ni = 0; ni < 4; ni++)
                acc[mi][ni] = MFMA16(af[mi], bfr[ni], acc[mi][ni], 0, 0, 0);
        __syncthreads();
    }

    if (EPI == 0) {
#pragma unroll
        for (int half = 0; half < 2; ++half) {
            if (wm == half) {
#pragma unroll
                for (int mi = 0; mi < 4; mi++)
#pragma unroll
                    for (int ni = 0; ni < 4; ni++) {
                        int lr = mi * 16 + ((lane >> 4) << 2);
                        int col = wn * 64 + ni * 16 + (lane & 15);
#pragma unroll
                        for (int rr = 0; rr < 4; rr++)
                            sm[(lr + rr) * 128 + col] = f2b(acc[mi][ni][rr]);
                    }
            }
            __syncthreads();
#pragma unroll
            for (int q = 0; q < 4; q++) {
                int lr = w * 16 + q * 4 + (lane >> 4);
                int colb = (lane & 15) * 16;
                int4 v = *(const int4*)((const char*)sm + lr * 256 + colb);
                char* gp = (char*)(Cb + (size_t)(row0 + half * 64 + lr) * ldc + col0) + colb;
                *(int4*)gp = v;
            }
            __syncthreads();
        }
    } else {
#pragma unroll
        for (int mi = 0; mi < 4; mi++)
#pragma unroll
            for (int ni = 0; ni < 4; ni++) {
                int mbase = row0 + wm * 64 + mi * 16 + ((lane >> 4) << 2);
                int n = col0 + wn * 64 + ni * 16 + (lane & 15);
#pragma unroll
                for (int rr = 0; rr < 4; rr++) {
                    size_t off = (size_t)(mbase + rr) * ldc + n;
                    if (KSPLIT == 1) Cf[off] += acc[mi][ni][rr];
                    else atomicAdd(Cf + off, acc[mi][ni][rr]);
                }
            }
    }
}

// ---------------- out-proj GEMM: res[m,n] += sum_k y2[m,k]*obf[n,k] ---------
// 128x64 tile, 512 blocks, KSPLIT=1, deterministic += (no atomics).
__global__ __launch_bounds__(256) void gemmo_k(const u16* __restrict__ A,
                                               const u16* __restrict__ Bw,
                                               float* __restrict__ Cf) {
    __shared__ u16 As[128 * 32];      // 8 KB
    __shared__ u16 Bs[64 * 32];       // 4 KB
    const int tid = threadIdx.x;
    const int lane = tid & 63;
    const int w = tid >> 6;
    const int wm = w >> 1, wn = w & 1;

    const int rowsPer = 4;
    const int xcd = blockIdx.x & 7;
    const int local = blockIdx.x >> 3;
    const int bx = local / rowsPer;
    const int by = xcd * rowsPer + (local % rowsPer);
    const int row0 = by << 7, col0 = bx << 6;

    const int srow = lane >> 2;          // 0..15
    const int skp  = (lane & 3) << 3;    // 0,8,16,24

    f32x4 zero = {0.f, 0.f, 0.f, 0.f};
    f32x4 acc[4][2];
#pragma unroll
    for (int i = 0; i < 4; i++)
#pragma unroll
        for (int j = 0; j < 2; j++) acc[i][j] = zero;

    const int tiles = DI >> 5;           // 64
    for (int kt = 0; kt < tiles; ++kt) {
        const int k0 = kt << 5;
#pragma unroll
        for (int j = 0; j < 2; ++j) {
            int r = w * 32 + j * 16 + srow;
            gload16(A + (size_t)(row0 + r) * DI + k0 + skp,
                    As + w * 1024 + j * 512);
        }
        {
            int r = w * 16 + srow;
            gload16(Bw + (size_t)(col0 + r) * DI + k0 + skp,
                    Bs + w * 512);
        }
        __syncthreads();
        bf16x8 af[4], bfr[2];
#pragma unroll
        for (int mi = 0; mi < 4; mi++) {
            int row = wm * 64 + mi * 16 + (lane & 15);
            af[mi] = *(const bf16x8*)(As + row * 32 + ((lane >> 4) << 3));
        }
#pragma unroll
        for (int ni = 0; ni < 2; ni++) {
            int row = wn * 32 + ni * 16 + (lane & 15);
            bfr[ni] = *(const bf16x8*)(Bs + row * 32 + ((lane >> 4) << 3));
        }
#pragma unroll
        for (int mi = 0; mi < 4; mi++)
#pragma unroll
            for (int ni = 0; ni < 2; ni++)
                acc[mi][ni] = MFMA16(af[mi], bfr[ni], acc[mi][ni], 0, 0, 0);
        __syncthreads();
    }

#pragma unroll
    for (int mi = 0; mi < 4; mi++)
#pragma unroll
        for (int ni = 0; ni < 2; ni++) {
            int mbase = row0 + wm * 64 + mi * 16 + ((lane >> 4) << 2);
            int n = col0 + wn * 32 + ni * 16 + (lane & 15);
#pragma unroll
            for (int rr = 0; rr < 4; rr++) {
                size_t off = (size_t)(mbase + rr) * DM + n;
                Cf[off] += acc[mi][ni][rr];
            }
        }
}

// ---------------- causal conv1d (K=4) + bias + SiLU, x8 vectorized ----------
// thread -> (t, 8-channel group); exact grid TOK*DCONV/8/256 = 4352 blocks
__global__ __launch_bounds__(256) void conv_k(const u16* __restrict__ zx,
                                              const float* __restrict__ cw,
                                              const float* __restrict__ cb,
                                              u16* __restrict__ xbc) {
    int idx = blockIdx.x * 256 + threadIdx.x;
    int c0 = (idx % (DCONV / 8)) * 8;
    int t  = idx / (DCONV / 8);
    int s = t % SEQ;
    float a[8];
    float4 wv[8];
#pragma unroll
    for (int j = 0; j < 8; j++) {
        a[j] = cb[c0 + j];
        wv[j] = *(const float4*)(cw + (c0 + j) * KC);
    }
#pragma unroll
    for (int k = 0; k < KC; k++) {
        int ss = s - 3 + k;
        if (ss >= 0) {
            int4 v = *(const int4*)(zx + (size_t)(t - 3 + k) * DINP + DI + c0);
            const u16* vp = (const u16*)&v;
#pragma unroll
            for (int j = 0; j < 8; j++) {
                float tap = (k == 0) ? wv[j].x : (k == 1) ? wv[j].y
                          : (k == 2) ? wv[j].z : wv[j].w;
                a[j] += tap * b2f(vp[j]);
            }
        }
    }
    u16 o[8];
#pragma unroll
    for (int j = 0; j < 8; j++) {
        float x = a[j];
        x = x / (1.f + __expf(-x));
        o[j] = f2b(x);
    }
    *(int4*)(xbc + (size_t)t * DCONV + c0) = *(const int4*)o;
}

// ---------------- dt/acum: LDS-staged parallel load + fast cumsum -----------
// block = b*NC + c ; 256 threads
__global__ __launch_bounds__(256) void dtacum_k(const u16* __restrict__ zx,
                                                const float* __restrict__ dtb,
                                                const float* __restrict__ alog,
                                                float* __restrict__ dt,
                                                float* __restrict__ acum) {
    __shared__ float raw[64][33], dts[64][33], acs[64][33];
    int bc = blockIdx.x;
    int t0 = bc * CHK;
    int tid = threadIdx.x;
#pragma unroll
    for (int it = 0; it < 8; ++it) {
        int idx = it * 256 + tid;
        int l = idx >> 5, h = idx & 31;
        raw[l][h] = b2f(zx[(size_t)(t0 + l) * DINP + DI + DCONV + h]);
    }
    __syncthreads();
    if (tid < NH) {
        int h = tid;
        float bias = dtb[h];
        float Ah = -__expf(alog[h]);
        float run = 0.f;
#pragma unroll 4
        for (int l = 0; l < CHK; l++) {
            float x = raw[l][h] + bias;
            float d = (x > 20.f) ? x : log1pf(__expf(x));
            dts[l][h] = d;
            run += d * Ah;
            acs[l][h] = run;
        }
    }
    __syncthreads();
#pragma unroll
    for (int it = 0; it < 8; ++it) {
        int idx = it * 256 + tid;
        int l = idx >> 5, h = idx & 31;
        dt[(size_t)(t0 + l) * NH + h] = dts[l][h];
        acum[(size_t)(t0 + l) * NH + h] = acs[l][h];
    }
}

// ---------------- intra-chunk via MFMA (exp-factorized) ---------------------
// block = (b*NC+c)*(NH/HPB) + hg ; heads h = hg*HPB + 0..HPB-1
__global__ __launch_bounds__(256) void ydiagm_k(const u16* __restrict__ xbc,
                                                const float* __restrict__ dt_,
                                                const float* __restrict__ acum,
                                                const float* __restrict__ Dw,
                                                float* __restrict__ yb,
                                                float* __restrict__ st) {
    __shared__ u16 Bl[8192/2], Cl[8192/2], BlT[8192/2], CBm[8192/2], XpT[8192/2];
    __shared__ float cs[2][64], rs[2][64];
    const int tid = threadIdx.x;
    const int lane = tid & 63;
    const int w = tid >> 6;
    const int blk = blockIdx.x;
    const int hg = blk & (NH / HPB - 1);
    const int bc = blk / (NH / HPB);
    const int t0 = bc * CHK;

    for (int it = 0; it < 8; ++it) {
        int idx2 = it * 256 + tid;
        int r = idx2 >> 5;
        int j0 = (idx2 & 31) * 2;
        size_t rowp = (size_t)(t0 + r) * DCONV;
        uint32_t bv = *(const uint32_t*)(xbc + rowp + DI + j0);
        uint32_t cv = *(const uint32_t*)(xbc + rowp + DI + DSTT + j0);
        st32(Bl, r, j0, bv);
        st32(Cl, r, j0, cv);
        st16(BlT, j0, r, (u16)(bv & 0xffff));
        st16(BlT, j0 + 1, r, (u16)(bv >> 16));
    }
    {
        int4 z4 = {0, 0, 0, 0};
        *(int4*)((char*)CBm + tid * 16) = z4;
        *(int4*)((char*)CBm + 4096 + tid * 16) = z4;
    }
    if (tid < 64) {
        int h0 = hg * HPB;
        float a = acum[(size_t)(t0 + tid) * NH + h0];
        float d = dt_[(size_t)(t0 + tid) * NH + h0];
        cs[0][tid] = __expf(-a) * d;
        rs[0][tid] = __expf(a);
    }
    __syncthreads();

    {
        bf16x8 a0 = ldfrag(Cl, w * 16, 0, lane);
        bf16x8 a1 = ldfrag(Cl, w * 16, 1, lane);
        for (int stt = 0; stt <= w; ++stt) {
            f32x4 acc = {0.f, 0.f, 0.f, 0.f};
            acc = MFMA16(a0, ldfrag(Bl, stt * 16, 0, lane), acc, 0, 0, 0);
            acc = MFMA16(a1, ldfrag(Bl, stt * 16, 1, lane), acc, 0, 0, 0);
            int lrow = w * 16 + ((lane >> 4) << 2);
            int scol = stt * 16 + (lane & 15);
#pragma unroll
            for (int rr = 0; rr < 4; rr++) {
                int lg = lrow + rr;
                u16 v = (scol <= lg) ? f2b(acc[rr]) : (u16)0;
                st16(CBm, lg, scol, v);
            }
        }
    }

    int cur = 0;
    for (int hh = 0; hh < HPB; ++hh) {
        const int h = hg * HPB + hh;
        const int nxt = cur ^ 1;
        for (int it = 0; it < 8; ++it) {
            int s0 = it * 8 + w * 2;
            float c0 = cs[cur][s0], c1 = cs[cur][s0 + 1];
            float x0 = b2f(xbc[(size_t)(t0 + s0) * DCONV + h * HP + lane]);
            float x1 = b2f(xbc[(size_t)(t0 + s0 + 1) * DCONV + h * HP + lane]);
            uint32_t pk = (uint32_t)f2b(c0 * x0) | ((uint32_t)f2b(c1 * x1) << 16);
            st32(XpT, lane, s0, pk);
        }
        if (hh < HPB - 1 && tid < 64) {
            float a = acum[(size_t)(t0 + tid) * NH + h + 1];
            float d = dt_[(size_t)(t0 + tid) * NH + h + 1];
            cs[nxt][tid] = __expf(-a) * d;
            rs[nxt][tid] = __expf(a);
        }
        __syncthreads();

        {
            float Dh = Dw[h];
#pragma unroll
            for (int nt = 0; nt < 4; ++nt) {
                f32x4 acc = {0.f, 0.f, 0.f, 0.f};
                acc = MFMA16(ldfrag(CBm, w * 16, 0, lane),
                             ldfrag(XpT, nt * 16, 0, lane), acc, 0, 0, 0);
                if (w >= 2)
                    acc = MFMA16(ldfrag(CBm, w * 16, 1, lane),
                                 ldfrag(XpT, nt * 16, 1, lane), acc, 0, 0, 0);
                int lrow = w * 16 + ((lane >> 4) << 2);
                int pg = nt * 16 + (lane & 15);
#pragma unroll
                for (int rr = 0; rr < 4; rr++) {
                    int lg = lrow + rr;
                    float xr = b2f(xbc[(size_t)(t0 + lg) * DCONV + h * HP + pg]);
                    yb[(size_t)(t0 + lg) * DI + h * HP + pg] =
                        rs[cur][lg] * acc[rr] + Dh * xr;
                }
            }
        }
        {
            float dcv = rs[cur][63];
            float* so = st + (size_t)(bc * NH + h) * (HP * DSTT);
            bf16x8 a0 = ldfrag(XpT, w * 16, 0, lane);
            bf16x8 a1 = ldfrag(XpT, w * 16, 1, lane);
#pragma unroll
            for (int nt = 0; nt < 4; ++nt) {
                f32x4 acc = {0.f, 0.f, 0.f, 0.f};
                acc = MFMA16(a0, ldfrag(BlT, nt * 16, 0, lane), acc, 0, 0, 0);
                acc = MFMA16(a1, ldfrag(BlT, nt * 16, 1, lane), acc, 0, 0, 0);
                int prow = w * 16 + ((lane >> 4) << 2);
                int ng = nt * 16 + (lane & 15);
#pragma unroll
                for (int rr = 0; rr < 4; rr++)
                    so[(size_t)(prow + rr) * DSTT + ng] = dcv * acc[rr];
            }
        }
        __syncthreads();
        cur ^= 1;
    }
}

// ---------------- element-parallel inter-chunk scan (in place) --------------
__global__ __launch_bounds__(256) void chainscan_k(const float* __restrict__ acum,
                                                   float* __restrict__ st) {
    __shared__ float dc[NC];
    int blk = blockIdx.x;
    int slice = blk & 15;
    int bh = blk >> 4;
    int h = bh % NH, b = bh / NH;
    int tid = threadIdx.x;
    if (tid < NC)
        dc[tid] = __expf(acum[(size_t)(b * SEQ + tid * CHK + CHK - 1) * NH + h]);
    __syncthreads();
    int e = slice * 256 + tid;
    float* p = st + ((size_t)(b * NC) * NH + h) * (HP * DSTT) + e;
    const size_t cstride = (size_t)NH * HP * DSTT;
    float s = 0.f;
#pragma unroll 4
    for (int c = 0; c < NC; c++) {
        float v = p[c * cstride];
        p[c * cstride] = s;
        s = dc[c] * s + v;
    }
}

// ---------------- y_off via MFMA: y[l,p] += ea[l]*sum_n C[l,n]*S_c[p,n] -----
// block = (b*NC + c)*NH + h ; 256 threads; A-tile = C rows, B-tile = S rows
__global__ __launch_bounds__(256) void yoffm_k(const u16* __restrict__ xbc,
                                               const float* __restrict__ acum,
                                               const float* __restrict__ S,
                                               float* __restrict__ yb) {
    __shared__ u16 Cl[4096], Sl[4096];   // two 64x64 bf16 tiles
    __shared__ float eal[64];
    const int blk = blockIdx.x;
    const int h = blk % NH;
    const int bc = blk / NH;
    const int t0 = bc * CHK;
    const int tid = threadIdx.x;
    const int lane = tid & 63;
    const int w = tid >> 6;

    for (int it = 0; it < 8; ++it) {
        int idx2 = it * 256 + tid;
        int r = idx2 >> 5;              // 0..63
        int j0 = (idx2 & 31) * 2;       // 0..62 even
        uint32_t cv = *(const uint32_t*)(xbc + (size_t)(t0 + r) * DCONV + DI + DSTT + j0);
        st32(Cl, r, j0, cv);
    }
    const float* Sp = S + (size_t)blk * (HP * DSTT);
    for (int it = 0; it < 8; ++it) {
        int idx2 = it * 256 + tid;
        int p = idx2 >> 5;
        int j0 = (idx2 & 31) * 2;
        float s0 = Sp[p * DSTT + j0];
        float s1 = Sp[p * DSTT + j0 + 1];
        st32(Sl, p, j0, (uint32_t)f2b(s0) | ((uint32_t)f2b(s1) << 16));
    }
    if (tid < 64) eal[tid] = __expf(acum[(size_t)(t0 + tid) * NH + h]);
    __syncthreads();

    bf16x8 a0 = ldfrag(Cl, w * 16, 0, lane);
    bf16x8 a1 = ldfrag(Cl, w * 16, 1, lane);
#pragma unroll
    for (int nt = 0; nt < 4; ++nt) {
        f32x4 acc = {0.f, 0.f, 0.f, 0.f};
        acc = MFMA16(a0, ldfrag(Sl, nt * 16, 0, lane), acc, 0, 0, 0);
        acc = MFMA16(a1, ldfrag(Sl, nt * 16, 1, lane), acc, 0, 0, 0);
        int lrow = w * 16 + ((lane >> 4) << 2);
        int pg = nt * 16 + (lane & 15);
#pragma unroll
        for (int rr = 0; rr < 4; rr++) {
            int lg = lrow + rr;
            yb[(size_t)(t0 + lg) * DI + h * HP + pg] += eal[lg] * acc[rr];
        }
    }
}

// ---------------- gate (y * silu(z)) + RMSNorm * rms_w -> bf16 --------------
__global__ __launch_bounds__(256) void gaterms_k(const float* __restrict__ yb,
                                                 const u16* __restrict__ zx,
                                                 const float* __restrict__ rw,
                                                 u16* __restrict__ y2) {
    __shared__ float red[4];
    int t = blockIdx.x, tid = threadIdx.x;
    const float* yr = yb + (size_t)t * DI;
    const u16* zr = zx + (size_t)t * DINP;
    int i0 = tid * 8;
    float g[8];
    float ss = 0.f;
#pragma unroll
    for (int j = 0; j < 8; j++) {
        float y = yr[i0 + j];
        float z = b2f(zr[i0 + j]);
        float sl = z / (1.f + __expf(-z));
        float v = y * sl;
        g[j] = v;
        ss += v * v;
    }
#pragma unroll
    for (int off = 32; off; off >>= 1) ss += __shfl_down(ss, off);
    if ((tid & 63) == 0) red[tid >> 6] = ss;
    __syncthreads();
    float tot = red[0] + red[1] + red[2] + red[3];
    float sc = rsqrtf(tot * (1.f / DI) + 1e-5f);
    u16* yo = y2 + (size_t)t * DI + i0;
#pragma unroll
    for (int j = 0; j < 8; j++) yo[j] = f2b(g[j] * sc * rw[i0 + j]);
}

// ============================ host-side launch ==============================
extern "C" void kernel_launch(void* const* d_in, const int* in_sizes, int n_in,
                              void* d_out, int out_size, void* d_ws, size_t ws_size,
                              hipStream_t stream) {
    const int*   ids      = (const int*)d_in[0];
    const float* emb      = (const float*)d_in[2];
    const float* ln_w     = (const float*)d_in[3];
    const float* ln_b     = (const float*)d_in[4];
    const float* in_w     = (const float*)d_in[5];
    const float* conv_w   = (const float*)d_in[6];
    const float* conv_b   = (const float*)d_in[7];
    const float* dt_bias  = (const float*)d_in[8];
    const float* A_log    = (const float*)d_in[9];
    const float* Dw       = (const float*)d_in[10];
    const float* rms_w    = (const float*)d_in[11];
    const float* out_w    = (const float*)d_in[12];
    const float* norm_w   = (const float*)d_in[13];
    const float* norm_b   = (const float*)d_in[14];

    char* ws = (char*)d_ws;
    float* res  = (float*)(ws);                    // 16,777,216 B
    u16*   zx   = (u16*)  (ws + 16777216);         // 35,651,584 B (stride DINP)
    u16*   xbc  = (u16*)  (ws + 52428800);         // 17,825,792 B
    u16*   obf  = (u16*)  (ws + 52428800);         // alias (4.2 MB, post-yoff)
    float* dt   = (float*)(ws + 70254592);         //    524,288 B
    float* acum = (float*)(ws + 70778880);         //    524,288 B
    float* yb   = (float*)(ws + 71303168);         // 33,554,432 B
    u16*   h    = (u16*)  (ws + 71303168);         // alias (8.4 MB, used pre-yb)
    float* st   = (float*)(ws + 104857600);        // 33,554,432 B
    u16*   y2   = (u16*)  (ws + 138412032);        // 16,777,216 B
    u16*   wpad = (u16*)  (ws + 138412032);        // alias (8.9 MB, used pre-y2)
    const size_t NEED = 155189248;
    if (ws_size < NEED) return;

    embed_k<<<TOK, 256, 0, stream>>>(ids, emb, res);

    for (int l = 0; l < NLAY; ++l) {
        ln_k<u16><<<TOK, 256, 0, stream>>>(res, ln_w + l * DM, ln_b + l * DM, h);
        padw_k<<<(DINP * DM / 4 + 255) / 256, 256, 0, stream>>>(
            in_w + (size_t)l * DINR * DM, wpad);
        gemm_k<0, 1><<<(TOK / 128) * (DINP / 128), 256, 0, stream>>>(
            h, wpad, zx, nullptr, DINP, DM, DINP);
        conv_k<<<TOK * DCONV / 8 / 256, 256, 0, stream>>>(
            zx, conv_w + (size_t)l * DCONV * KC, conv_b + (size_t)l * DCONV, xbc);
        dtacum_k<<<BATCH * NC, 256, 0, stream>>>(
            zx, dt_bias + l * NH, A_log + l * NH, dt, acum);
        ydiagm_k<<<BATCH * NC * (NH / HPB), 256, 0, stream>>>(
            xbc, dt, acum, Dw + l * NH, yb, st);
        chainscan_k<<<BATCH * NH * 16, 256, 0, stream>>>(acum, st);
        yoffm_k<<<BATCH * NC * NH, 256, 0, stream>>>(xbc, acum, st, yb);
        gaterms_k<<<TOK, 256, 0, stream>>>(yb, zx, rms_w + (size_t)l * DI, y2);
        cvt_k<<<(DM * DI / 4 + 255) / 256, 256, 0, stream>>>(
            out_w + (size_t)l * DM * DI, obf, DM * DI);
        gemmo_k<<<512, 256, 0, stream>>>(y2, obf, res);
    }

    ln_k<float><<<TOK, 256, 0, stream>>>(res, norm_w, norm_b, (float*)d_out);
}

// Round 19
// 924.047 us; speedup vs baseline: 1.0308x; 1.0308x over previous
//
#include <hip/hip_runtime.h>
#include <stdint.h>

typedef unsigned short u16;
using bf16x8 = __attribute__((ext_vector_type(8))) short;
using f32x4  = __attribute__((ext_vector_type(4))) float;

#define BATCH 2
#define SEQ   2048
#define TOK   (BATCH*SEQ)      // 4096 tokens
#define DM    1024
#define NLAY  4
#define DI    2048
#define DSTT  64               // state dim DS
#define NH    32               // heads
#define HP    64               // head dim P
#define KC    4                // conv kernel
#define CHK   64               // chunk len
#define NC    (SEQ/CHK)        // 32 chunks
#define DCONV (DI + 2*DSTT)    // 2176
#define DINR  (2*DI + 2*DSTT + NH) // 4256
#define DINP  4352             // padded to 128 multiple
#define HPB   4                // heads per ydiagm block

#define MFMA16 __builtin_amdgcn_mfma_f32_16x16x32_bf16

__device__ __forceinline__ float b2f(u16 u) {
    union { uint32_t i; float f; } v; v.i = ((uint32_t)u) << 16; return v.f;
}
__device__ __forceinline__ u16 f2b(float f) {
    union { float f; uint32_t i; } v; v.f = f;
    uint32_t x = v.i;
    uint32_t r = x + 0x7fffu + ((x >> 16) & 1u);
    return (u16)(r >> 16);
}
__device__ __forceinline__ void gload16(const u16* g, u16* l) {
    __builtin_amdgcn_global_load_lds(
        (const __attribute__((address_space(1))) void*)g,
        (__attribute__((address_space(3))) void*)l, 16, 0, 0);
}
// ---- 64x64 bf16 operand tiles: [2 k-tiles][64 rows][32 cols], gemm swizzle --
__device__ __forceinline__ int swzb(int byo) {
    return byo ^ (((byo >> 6) & 7) << 4);
}
__device__ __forceinline__ void st16(u16* base, int r, int k, u16 v) {
    int byo = ((k >> 5) << 12) | ((r * 32 + (k & 31)) << 1);
    *(u16*)((char*)base + swzb(byo)) = v;
}
__device__ __forceinline__ void st32(u16* base, int r, int k, uint32_t v) {
    int byo = ((k >> 5) << 12) | ((r * 32 + (k & 31)) << 1);   // k even
    *(uint32_t*)((char*)base + swzb(byo)) = v;
}
__device__ __forceinline__ bf16x8 ldfrag(const u16* base, int rbase, int kt, int lane) {
    int byo = (kt << 12) | (((rbase + (lane & 15)) * 32 + ((lane >> 4) << 3)) << 1);
    return *(const bf16x8*)((const char*)base + swzb(byo));
}

// ---------------- embedding gather: res[t,:] = emb[ids[t],:] (f32) ----------
__global__ __launch_bounds__(256) void embed_k(const int* __restrict__ ids,
                                               const float* __restrict__ emb,
                                               float* __restrict__ res) {
    int t = blockIdx.x, tid = threadIdx.x;
    int id = ids[t];
    const float* er = emb + (size_t)id * DM;
    int i0 = tid * 4;
    *(float4*)(res + (size_t)t * DM + i0) = *(const float4*)(er + i0);
}

// ---------------- layernorm over DM: src f32 -> dst (bf16 or f32) -----------
template <typename OutT>
__global__ __launch_bounds__(256) void ln_k(const float* __restrict__ src,
                                            const float* __restrict__ w,
                                            const float* __restrict__ bb,
                                            OutT* __restrict__ dst) {
    __shared__ float r1[4], r2[4];
    int t = blockIdx.x, tid = threadIdx.x;
    const float* x = src + (size_t)t * DM;
    int i0 = tid * 4;
    float4 v = *(const float4*)(x + i0);
    float s1 = v.x + v.y + v.z + v.w;
    float s2 = v.x * v.x + v.y * v.y + v.z * v.z + v.w * v.w;
#pragma unroll
    for (int off = 32; off; off >>= 1) {
        s1 += __shfl_down(s1, off);
        s2 += __shfl_down(s2, off);
    }
    if ((tid & 63) == 0) { r1[tid >> 6] = s1; r2[tid >> 6] = s2; }
    __syncthreads();
    float S1 = r1[0] + r1[1] + r1[2] + r1[3];
    float S2 = r2[0] + r2[1] + r2[2] + r2[3];
    float mean = S1 * (1.f / DM);
    float var = S2 * (1.f / DM) - mean * mean;
    float inv = rsqrtf(var + 1e-5f);
    float4 wv = *(const float4*)(w + i0);
    float4 bv = *(const float4*)(bb + i0);
    OutT* d = dst + (size_t)t * DM + i0;
    float o0 = (v.x - mean) * inv * wv.x + bv.x;
    float o1 = (v.y - mean) * inv * wv.y + bv.y;
    float o2 = (v.z - mean) * inv * wv.z + bv.z;
    float o3 = (v.w - mean) * inv * wv.w + bv.w;
    if constexpr (sizeof(OutT) == 2) {
        d[0] = f2b(o0); d[1] = f2b(o1); d[2] = f2b(o2); d[3] = f2b(o3);
    } else {
        float4 o; o.x = o0; o.y = o1; o.z = o2; o.w = o3;
        *(float4*)d = o;
    }
}

// ------- pad+convert ALL layers in_w (f32) -> wpadAll (bf16, 4x4352x1024) ---
__global__ __launch_bounds__(256) void padw4_k(const float* __restrict__ w,
                                               u16* __restrict__ wp) {
    int idx = (blockIdx.x * 256 + threadIdx.x) * 4;
    int l = idx / (DINP * DM);
    int rem = idx - l * (DINP * DM);
    u16* dst = wp + (size_t)l * DINP * DM + rem;
    if (rem < DINR * DM) {
        float4 v = *(const float4*)(w + (size_t)l * DINR * DM + rem);
        dst[0] = f2b(v.x); dst[1] = f2b(v.y);
        dst[2] = f2b(v.z); dst[3] = f2b(v.w);
    } else {
        dst[0] = 0; dst[1] = 0; dst[2] = 0; dst[3] = 0;
    }
}

// ------- convert ALL layers out_w (f32) -> obfAll (bf16, 4x1024x2048) -------
__global__ __launch_bounds__(256) void cvt4_k(const float* __restrict__ src,
                                              u16* __restrict__ dst) {
    int idx = (blockIdx.x * 256 + threadIdx.x) * 4;
    float4 v = *(const float4*)(src + idx);
    dst[idx + 0] = f2b(v.x); dst[idx + 1] = f2b(v.y);
    dst[idx + 2] = f2b(v.z); dst[idx + 3] = f2b(v.w);
}

// ---------------- bf16 GEMM (m97 structure): C[m,n] = sum_k A[m,k]*B[n,k] ---
// Used only as gemm_k<0,1> (in-proj, bf16 LDS-coalesced store) — proven form.
template <int EPI, int KSPLIT>
__global__ __launch_bounds__(256) void gemm_k(const u16* __restrict__ A,
                                              const u16* __restrict__ Bw,
                                              u16* __restrict__ Cb,
                                              float* __restrict__ Cf,
                                              int N, int Kd, int ldc) {
    __shared__ u16 sm[8192];          // As = sm[0:4096], Bs = sm[4096:8192]
    u16* As = sm;
    u16* Bs = sm + 4096;
    const int tid = threadIdx.x;
    const int lane = tid & 63;
    const int w = tid >> 6;
    const int wm = w >> 1, wn = w & 1;
    const int nb = N >> 7;

    const int rowsPer = (gridDim.x / nb) >> 3;
    const int xcd = blockIdx.x & 7;
    const int local = blockIdx.x >> 3;
    const int bx = local / rowsPer;
    const int by = xcd * rowsPer + (local % rowsPer);
    const int row0 = by << 7, col0 = bx << 7;

    const int Kslice = Kd / KSPLIT;
    const int kbase = blockIdx.y * Kslice;

    const int srow = lane >> 2;
    const int skp  = (lane & 3) << 3;

    f32x4 zero = {0.f, 0.f, 0.f, 0.f};
    f32x4 acc[4][4];
#pragma unroll
    for (int i = 0; i < 4; i++)
#pragma unroll
        for (int j = 0; j < 4; j++) acc[i][j] = zero;

    const int tiles = Kslice >> 5;
    for (int kt = 0; kt < tiles; ++kt) {
        const int k0 = kbase + (kt << 5);
#pragma unroll
        for (int j = 0; j < 2; ++j) {
            int r = w * 32 + j * 16 + srow;
            gload16(A + (size_t)(row0 + r) * Kd + k0 + skp,
                    As + w * 1024 + j * 512);
            gload16(Bw + (size_t)(col0 + r) * Kd + k0 + skp,
                    Bs + w * 1024 + j * 512);
        }
        __syncthreads();
        bf16x8 af[4], bfr[4];
#pragma unroll
        for (int mi = 0; mi < 4; mi++) {
            int row = wm * 64 + mi * 16 + (lane & 15);
            af[mi] = *(const bf16x8*)(As + row * 32 + ((lane >> 4) << 3));
        }
#pragma unroll
        for (int ni = 0; ni < 4; ni++) {
            int row = wn * 64 + ni * 16 + (lane & 15);
            bfr[ni] = *(const bf16x8*)(Bs + row * 32 + ((lane >> 4) << 3));
        }
#pragma unroll
        for (int mi = 0; mi < 4; mi++)
#pragma unroll
            for (int ni = 0; ni < 4; ni++)
                acc[mi][ni] = MFMA16(af[mi], bfr[ni], acc[mi][ni], 0, 0, 0);
        __syncthreads();
    }

    if (EPI == 0) {
#pragma unroll
        for (int half = 0; half < 2; ++half) {
            if (wm == half) {
#pragma unroll
                for (int mi = 0; mi < 4; mi++)
#pragma unroll
                    for (int ni = 0; ni < 4; ni++) {
                        int lr = mi * 16 + ((lane >> 4) << 2);
                        int col = wn * 64 + ni * 16 + (lane & 15);
#pragma unroll
                        for (int rr = 0; rr < 4; rr++)
                            sm[(lr + rr) * 128 + col] = f2b(acc[mi][ni][rr]);
                    }
            }
            __syncthreads();
#pragma unroll
            for (int q = 0; q < 4; q++) {
                int lr = w * 16 + q * 4 + (lane >> 4);
                int colb = (lane & 15) * 16;
                int4 v = *(const int4*)((const char*)sm + lr * 256 + colb);
                char* gp = (char*)(Cb + (size_t)(row0 + half * 64 + lr) * ldc + col0) + colb;
                *(int4*)gp = v;
            }
            __syncthreads();
        }
    } else {
#pragma unroll
        for (int mi = 0; mi < 4; mi++)
#pragma unroll
            for (int ni = 0; ni < 4; ni++) {
                int mbase = row0 + wm * 64 + mi * 16 + ((lane >> 4) << 2);
                int n = col0 + wn * 64 + ni * 16 + (lane & 15);
#pragma unroll
                for (int rr = 0; rr < 4; rr++) {
                    size_t off = (size_t)(mbase + rr) * ldc + n;
                    if (KSPLIT == 1) Cf[off] += acc[mi][ni][rr];
                    else atomicAdd(Cf + off, acc[mi][ni][rr]);
                }
            }
    }
}

// ---------------- out-proj GEMM: res[m,n] += sum_k y2[m,k]*obf[n,k] ---------
// 128x64 tile, 512 blocks, KSPLIT=1, deterministic += (no atomics).
__global__ __launch_bounds__(256) void gemmo_k(const u16* __restrict__ A,
                                               const u16* __restrict__ Bw,
                                               float* __restrict__ Cf) {
    __shared__ u16 As[128 * 32];      // 8 KB
    __shared__ u16 Bs[64 * 32];       // 4 KB
    const int tid = threadIdx.x;
    const int lane = tid & 63;
    const int w = tid >> 6;
    const int wm = w >> 1, wn = w & 1;

    const int rowsPer = 4;
    const int xcd = blockIdx.x & 7;
    const int local = blockIdx.x >> 3;
    const int bx = local / rowsPer;
    const int by = xcd * rowsPer + (local % rowsPer);
    const int row0 = by << 7, col0 = bx << 6;

    const int srow = lane >> 2;          // 0..15
    const int skp  = (lane & 3) << 3;    // 0,8,16,24

    f32x4 zero = {0.f, 0.f, 0.f, 0.f};
    f32x4 acc[4][2];
#pragma unroll
    for (int i = 0; i < 4; i++)
#pragma unroll
        for (int j = 0; j < 2; j++) acc[i][j] = zero;

    const int tiles = DI >> 5;           // 64
    for (int kt = 0; kt < tiles; ++kt) {
        const int k0 = kt << 5;
#pragma unroll
        for (int j = 0; j < 2; ++j) {
            int r = w * 32 + j * 16 + srow;
            gload16(A + (size_t)(row0 + r) * DI + k0 + skp,
                    As + w * 1024 + j * 512);
        }
        {
            int r = w * 16 + srow;
            gload16(Bw + (size_t)(col0 + r) * DI + k0 + skp,
                    Bs + w * 512);
        }
        __syncthreads();
        bf16x8 af[4], bfr[2];
#pragma unroll
        for (int mi = 0; mi < 4; mi++) {
            int row = wm * 64 + mi * 16 + (lane & 15);
            af[mi] = *(const bf16x8*)(As + row * 32 + ((lane >> 4) << 3));
        }
#pragma unroll
        for (int ni = 0; ni < 2; ni++) {
            int row = wn * 32 + ni * 16 + (lane & 15);
            bfr[ni] = *(const bf16x8*)(Bs + row * 32 + ((lane >> 4) << 3));
        }
#pragma unroll
        for (int mi = 0; mi < 4; mi++)
#pragma unroll
            for (int ni = 0; ni < 2; ni++)
                acc[mi][ni] = MFMA16(af[mi], bfr[ni], acc[mi][ni], 0, 0, 0);
        __syncthreads();
    }

#pragma unroll
    for (int mi = 0; mi < 4; mi++)
#pragma unroll
        for (int ni = 0; ni < 2; ni++) {
            int mbase = row0 + wm * 64 + mi * 16 + ((lane >> 4) << 2);
            int n = col0 + wn * 32 + ni * 16 + (lane & 15);
#pragma unroll
            for (int rr = 0; rr < 4; rr++) {
                size_t off = (size_t)(mbase + rr) * DM + n;
                Cf[off] += acc[mi][ni][rr];
            }
        }
}

// ---------------- causal conv1d (K=4) + bias + SiLU, x4 vectorized ----------
// thread -> (t, 4-channel group); exact grid TOK*DCONV/4/256 = 8704 blocks
__global__ __launch_bounds__(256) void conv_k(const u16* __restrict__ zx,
                                              const float* __restrict__ cw,
                                              const float* __restrict__ cb,
                                              u16* __restrict__ xbc) {
    int idx = blockIdx.x * 256 + threadIdx.x;
    int c0 = (idx % (DCONV / 4)) * 4;
    int t  = idx / (DCONV / 4);
    int s = t % SEQ;
    float a0 = cb[c0 + 0], a1 = cb[c0 + 1], a2 = cb[c0 + 2], a3 = cb[c0 + 3];
    float4 w0 = *(const float4*)(cw + (c0 + 0) * KC);
    float4 w1 = *(const float4*)(cw + (c0 + 1) * KC);
    float4 w2 = *(const float4*)(cw + (c0 + 2) * KC);
    float4 w3 = *(const float4*)(cw + (c0 + 3) * KC);
#pragma unroll
    for (int k = 0; k < KC; k++) {
        int ss = s - 3 + k;
        if (ss >= 0) {
            ushort4 v = *(const ushort4*)(zx + (size_t)(t - 3 + k) * DINP + DI + c0);
            float tap0 = (k == 0) ? w0.x : (k == 1) ? w0.y : (k == 2) ? w0.z : w0.w;
            float tap1 = (k == 0) ? w1.x : (k == 1) ? w1.y : (k == 2) ? w1.z : w1.w;
            float tap2 = (k == 0) ? w2.x : (k == 1) ? w2.y : (k == 2) ? w2.z : w2.w;
            float tap3 = (k == 0) ? w3.x : (k == 1) ? w3.y : (k == 2) ? w3.z : w3.w;
            a0 += tap0 * b2f(v.x);
            a1 += tap1 * b2f(v.y);
            a2 += tap2 * b2f(v.z);
            a3 += tap3 * b2f(v.w);
        }
    }
    a0 = a0 / (1.f + __expf(-a0));
    a1 = a1 / (1.f + __expf(-a1));
    a2 = a2 / (1.f + __expf(-a2));
    a3 = a3 / (1.f + __expf(-a3));
    ushort4 o;
    o.x = f2b(a0); o.y = f2b(a1); o.z = f2b(a2); o.w = f2b(a3);
    *(ushort4*)(xbc + (size_t)t * DCONV + c0) = o;
}

// ---------------- dt/acum: LDS-staged parallel load + fast cumsum -----------
// block = b*NC + c ; 256 threads
__global__ __launch_bounds__(256) void dtacum_k(const u16* __restrict__ zx,
                                                const float* __restrict__ dtb,
                                                const float* __restrict__ alog,
                                                float* __restrict__ dt,
                                                float* __restrict__ acum) {
    __shared__ float raw[64][33], dts[64][33], acs[64][33];
    int bc = blockIdx.x;
    int t0 = bc * CHK;
    int tid = threadIdx.x;
#pragma unroll
    for (int it = 0; it < 8; ++it) {
        int idx = it * 256 + tid;
        int l = idx >> 5, h = idx & 31;
        raw[l][h] = b2f(zx[(size_t)(t0 + l) * DINP + DI + DCONV + h]);
    }
    __syncthreads();
    if (tid < NH) {
        int h = tid;
        float bias = dtb[h];
        float Ah = -__expf(alog[h]);
        float run = 0.f;
#pragma unroll 4
        for (int l = 0; l < CHK; l++) {
            float x = raw[l][h] + bias;
            float d = (x > 20.f) ? x : log1pf(__expf(x));
            dts[l][h] = d;
            run += d * Ah;
            acs[l][h] = run;
        }
    }
    __syncthreads();
#pragma unroll
    for (int it = 0; it < 8; ++it) {
        int idx = it * 256 + tid;
        int l = idx >> 5, h = idx & 31;
        dt[(size_t)(t0 + l) * NH + h] = dts[l][h];
        acum[(size_t)(t0 + l) * NH + h] = acs[l][h];
    }
}

// ---------------- intra-chunk via MFMA (exp-factorized) ---------------------
// block = (b*NC+c)*(NH/HPB) + hg ; heads h = hg*HPB + 0..HPB-1
__global__ __launch_bounds__(256) void ydiagm_k(const u16* __restrict__ xbc,
                                                const float* __restrict__ dt_,
                                                const float* __restrict__ acum,
                                                const float* __restrict__ Dw,
                                                float* __restrict__ yb,
                                                float* __restrict__ st) {
    __shared__ u16 Bl[8192/2], Cl[8192/2], BlT[8192/2], CBm[8192/2], XpT[8192/2];
    __shared__ float cs[2][64], rs[2][64];
    const int tid = threadIdx.x;
    const int lane = tid & 63;
    const int w = tid >> 6;
    const int blk = blockIdx.x;
    const int hg = blk & (NH / HPB - 1);
    const int bc = blk / (NH / HPB);
    const int t0 = bc * CHK;

    for (int it = 0; it < 8; ++it) {
        int idx2 = it * 256 + tid;
        int r = idx2 >> 5;
        int j0 = (idx2 & 31) * 2;
        size_t rowp = (size_t)(t0 + r) * DCONV;
        uint32_t bv = *(const uint32_t*)(xbc + rowp + DI + j0);
        uint32_t cv = *(const uint32_t*)(xbc + rowp + DI + DSTT + j0);
        st32(Bl, r, j0, bv);
        st32(Cl, r, j0, cv);
        st16(BlT, j0, r, (u16)(bv & 0xffff));
        st16(BlT, j0 + 1, r, (u16)(bv >> 16));
    }
    {
        int4 z4 = {0, 0, 0, 0};
        *(int4*)((char*)CBm + tid * 16) = z4;
        *(int4*)((char*)CBm + 4096 + tid * 16) = z4;
    }
    if (tid < 64) {
        int h0 = hg * HPB;
        float a = acum[(size_t)(t0 + tid) * NH + h0];
        float d = dt_[(size_t)(t0 + tid) * NH + h0];
        cs[0][tid] = __expf(-a) * d;
        rs[0][tid] = __expf(a);
    }
    __syncthreads();

    {
        bf16x8 a0 = ldfrag(Cl, w * 16, 0, lane);
        bf16x8 a1 = ldfrag(Cl, w * 16, 1, lane);
        for (int stt = 0; stt <= w; ++stt) {
            f32x4 acc = {0.f, 0.f, 0.f, 0.f};
            acc = MFMA16(a0, ldfrag(Bl, stt * 16, 0, lane), acc, 0, 0, 0);
            acc = MFMA16(a1, ldfrag(Bl, stt * 16, 1, lane), acc, 0, 0, 0);
            int lrow = w * 16 + ((lane >> 4) << 2);
            int scol = stt * 16 + (lane & 15);
#pragma unroll
            for (int rr = 0; rr < 4; rr++) {
                int lg = lrow + rr;
                u16 v = (scol <= lg) ? f2b(acc[rr]) : (u16)0;
                st16(CBm, lg, scol, v);
            }
        }
    }

    int cur = 0;
    for (int hh = 0; hh < HPB; ++hh) {
        const int h = hg * HPB + hh;
        const int nxt = cur ^ 1;
        for (int it = 0; it < 8; ++it) {
            int s0 = it * 8 + w * 2;
            float c0 = cs[cur][s0], c1 = cs[cur][s0 + 1];
            float x0 = b2f(xbc[(size_t)(t0 + s0) * DCONV + h * HP + lane]);
            float x1 = b2f(xbc[(size_t)(t0 + s0 + 1) * DCONV + h * HP + lane]);
            uint32_t pk = (uint32_t)f2b(c0 * x0) | ((uint32_t)f2b(c1 * x1) << 16);
            st32(XpT, lane, s0, pk);
        }
        if (hh < HPB - 1 && tid < 64) {
            float a = acum[(size_t)(t0 + tid) * NH + h + 1];
            float d = dt_[(size_t)(t0 + tid) * NH + h + 1];
            cs[nxt][tid] = __expf(-a) * d;
            rs[nxt][tid] = __expf(a);
        }
        __syncthreads();

        {
            float Dh = Dw[h];
#pragma unroll
            for (int nt = 0; nt < 4; ++nt) {
                f32x4 acc = {0.f, 0.f, 0.f, 0.f};
                acc = MFMA16(ldfrag(CBm, w * 16, 0, lane),
                             ldfrag(XpT, nt * 16, 0, lane), acc, 0, 0, 0);
                if (w >= 2)
                    acc = MFMA16(ldfrag(CBm, w * 16, 1, lane),
                                 ldfrag(XpT, nt * 16, 1, lane), acc, 0, 0, 0);
                int lrow = w * 16 + ((lane >> 4) << 2);
                int pg = nt * 16 + (lane & 15);
#pragma unroll
                for (int rr = 0; rr < 4; rr++) {
                    int lg = lrow + rr;
                    float xr = b2f(xbc[(size_t)(t0 + lg) * DCONV + h * HP + pg]);
                    yb[(size_t)(t0 + lg) * DI + h * HP + pg] =
                        rs[cur][lg] * acc[rr] + Dh * xr;
                }
            }
        }
        {
            float dcv = rs[cur][63];
            float* so = st + (size_t)(bc * NH + h) * (HP * DSTT);
            bf16x8 a0 = ldfrag(XpT, w * 16, 0, lane);
            bf16x8 a1 = ldfrag(XpT, w * 16, 1, lane);
#pragma unroll
            for (int nt = 0; nt < 4; ++nt) {
                f32x4 acc = {0.f, 0.f, 0.f, 0.f};
                acc = MFMA16(a0, ldfrag(BlT, nt * 16, 0, lane), acc, 0, 0, 0);
                acc = MFMA16(a1, ldfrag(BlT, nt * 16, 1, lane), acc, 0, 0, 0);
                int prow = w * 16 + ((lane >> 4) << 2);
                int ng = nt * 16 + (lane & 15);
#pragma unroll
                for (int rr = 0; rr < 4; rr++)
                    so[(size_t)(prow + rr) * DSTT + ng] = dcv * acc[rr];
            }
        }
        __syncthreads();
        cur ^= 1;
    }
}

// ---------------- element-parallel inter-chunk scan (in place) --------------
__global__ __launch_bounds__(256) void chainscan_k(const float* __restrict__ acum,
                                                   float* __restrict__ st) {
    __shared__ float dc[NC];
    int blk = blockIdx.x;
    int slice = blk & 15;
    int bh = blk >> 4;
    int h = bh % NH, b = bh / NH;
    int tid = threadIdx.x;
    if (tid < NC)
        dc[tid] = __expf(acum[(size_t)(b * SEQ + tid * CHK + CHK - 1) * NH + h]);
    __syncthreads();
    int e = slice * 256 + tid;
    float* p = st + ((size_t)(b * NC) * NH + h) * (HP * DSTT) + e;
    const size_t cstride = (size_t)NH * HP * DSTT;
    float s = 0.f;
#pragma unroll 4
    for (int c = 0; c < NC; c++) {
        float v = p[c * cstride];
        p[c * cstride] = s;
        s = dc[c] * s + v;
    }
}

// ---------------- y_off via MFMA: y[l,p] += ea[l]*sum_n C[l,n]*S_c[p,n] -----
// block = (b*NC + c)*NH + h ; 256 threads; A-tile = C rows, B-tile = S rows
__global__ __launch_bounds__(256) void yoffm_k(const u16* __restrict__ xbc,
                                               const float* __restrict__ acum,
                                               const float* __restrict__ S,
                                               float* __restrict__ yb) {
    __shared__ u16 Cl[4096], Sl[4096];   // two 64x64 bf16 tiles
    __shared__ float eal[64];
    const int blk = blockIdx.x;
    const int h = blk % NH;
    const int bc = blk / NH;
    const int t0 = bc * CHK;
    const int tid = threadIdx.x;
    const int lane = tid & 63;
    const int w = tid >> 6;

    for (int it = 0; it < 8; ++it) {
        int idx2 = it * 256 + tid;
        int r = idx2 >> 5;              // 0..63
        int j0 = (idx2 & 31) * 2;       // 0..62 even
        uint32_t cv = *(const uint32_t*)(xbc + (size_t)(t0 + r) * DCONV + DI + DSTT + j0);
        st32(Cl, r, j0, cv);
    }
    const float* Sp = S + (size_t)blk * (HP * DSTT);
    for (int it = 0; it < 8; ++it) {
        int idx2 = it * 256 + tid;
        int p = idx2 >> 5;
        int j0 = (idx2 & 31) * 2;
        float s0 = Sp[p * DSTT + j0];
        float s1 = Sp[p * DSTT + j0 + 1];
        st32(Sl, p, j0, (uint32_t)f2b(s0) | ((uint32_t)f2b(s1) << 16));
    }
    if (tid < 64) eal[tid] = __expf(acum[(size_t)(t0 + tid) * NH + h]);
    __syncthreads();

    bf16x8 a0 = ldfrag(Cl, w * 16, 0, lane);
    bf16x8 a1 = ldfrag(Cl, w * 16, 1, lane);
#pragma unroll
    for (int nt = 0; nt < 4; ++nt) {
        f32x4 acc = {0.f, 0.f, 0.f, 0.f};
        acc = MFMA16(a0, ldfrag(Sl, nt * 16, 0, lane), acc, 0, 0, 0);
        acc = MFMA16(a1, ldfrag(Sl, nt * 16, 1, lane), acc, 0, 0, 0);
        int lrow = w * 16 + ((lane >> 4) << 2);
        int pg = nt * 16 + (lane & 15);
#pragma unroll
        for (int rr = 0; rr < 4; rr++) {
            int lg = lrow + rr;
            yb[(size_t)(t0 + lg) * DI + h * HP + pg] += eal[lg] * acc[rr];
        }
    }
}

// ---------------- gate (y * silu(z)) + RMSNorm * rms_w -> bf16 --------------
__global__ __launch_bounds__(256) void gaterms_k(const float* __restrict__ yb,
                                                 const u16* __restrict__ zx,
                                                 const float* __restrict__ rw,
                                                 u16* __restrict__ y2) {
    __shared__ float red[4];
    int t = blockIdx.x, tid = threadIdx.x;
    const float* yr = yb + (size_t)t * DI;
    const u16* zr = zx + (size_t)t * DINP;
    int i0 = tid * 8;
    float g[8];
    float ss = 0.f;
#pragma unroll
    for (int j = 0; j < 8; j++) {
        float y = yr[i0 + j];
        float z = b2f(zr[i0 + j]);
        float sl = z / (1.f + __expf(-z));
        float v = y * sl;
        g[j] = v;
        ss += v * v;
    }
#pragma unroll
    for (int off = 32; off; off >>= 1) ss += __shfl_down(ss, off);
    if ((tid & 63) == 0) red[tid >> 6] = ss;
    __syncthreads();
    float tot = red[0] + red[1] + red[2] + red[3];
    float sc = rsqrtf(tot * (1.f / DI) + 1e-5f);
    u16* yo = y2 + (size_t)t * DI + i0;
#pragma unroll
    for (int j = 0; j < 8; j++) yo[j] = f2b(g[j] * sc * rw[i0 + j]);
}

// ============================ host-side launch ==============================
extern "C" void kernel_launch(void* const* d_in, const int* in_sizes, int n_in,
                              void* d_out, int out_size, void* d_ws, size_t ws_size,
                              hipStream_t stream) {
    const int*   ids      = (const int*)d_in[0];
    const float* emb      = (const float*)d_in[2];
    const float* ln_w     = (const float*)d_in[3];
    const float* ln_b     = (const float*)d_in[4];
    const float* in_w     = (const float*)d_in[5];
    const float* conv_w   = (const float*)d_in[6];
    const float* conv_b   = (const float*)d_in[7];
    const float* dt_bias  = (const float*)d_in[8];
    const float* A_log    = (const float*)d_in[9];
    const float* Dw       = (const float*)d_in[10];
    const float* rms_w    = (const float*)d_in[11];
    const float* out_w    = (const float*)d_in[12];
    const float* norm_w   = (const float*)d_in[13];
    const float* norm_b   = (const float*)d_in[14];

    char* ws = (char*)d_ws;
    float* res    = (float*)(ws);                  // 16,777,216 B
    u16*   zx     = (u16*)  (ws + 16777216);       // 35,651,584 B (stride DINP)
    u16*   xbc    = (u16*)  (ws + 52428800);       // 17,825,792 B
    float* dt     = (float*)(ws + 70254592);       //    524,288 B
    float* acum   = (float*)(ws + 70778880);       //    524,288 B
    float* yb     = (float*)(ws + 71303168);       // 33,554,432 B
    u16*   h      = (u16*)  (ws + 71303168);       // alias (8.4 MB, used pre-yb)
    float* st     = (float*)(ws + 104857600);      // 33,554,432 B
    u16*   y2     = (u16*)  (ws + 138412032);      // 16,777,216 B
    u16*   wpadAll= (u16*)  (ws + 155189248);      // 35,651,584 B (4 layers)
    u16*   obfAll = (u16*)  (ws + 190840832);      // 16,777,216 B (4 layers)
    const size_t NEED = 207618048;
    if (ws_size < NEED) return;

    // one-shot weight conversions (all layers)
    padw4_k<<<NLAY * DINP * DM / 4 / 256, 256, 0, stream>>>(in_w, wpadAll);
    cvt4_k<<<NLAY * DM * DI / 4 / 256, 256, 0, stream>>>(out_w, obfAll);

    embed_k<<<TOK, 256, 0, stream>>>(ids, emb, res);

    for (int l = 0; l < NLAY; ++l) {
        ln_k<u16><<<TOK, 256, 0, stream>>>(res, ln_w + l * DM, ln_b + l * DM, h);
        gemm_k<0, 1><<<(TOK / 128) * (DINP / 128), 256, 0, stream>>>(
            h, wpadAll + (size_t)l * DINP * DM, zx, nullptr, DINP, DM, DINP);
        conv_k<<<TOK * DCONV / 4 / 256, 256, 0, stream>>>(
            zx, conv_w + (size_t)l * DCONV * KC, conv_b + (size_t)l * DCONV, xbc);
        dtacum_k<<<BATCH * NC, 256, 0, stream>>>(
            zx, dt_bias + l * NH, A_log + l * NH, dt, acum);
        ydiagm_k<<<BATCH * NC * (NH / HPB), 256, 0, stream>>>(
            xbc, dt, acum, Dw + l * NH, yb, st);
        chainscan_k<<<BATCH * NH * 16, 256, 0, stream>>>(acum, st);
        yoffm_k<<<BATCH * NC * NH, 256, 0, stream>>>(xbc, acum, st, yb);
        gaterms_k<<<TOK, 256, 0, stream>>>(yb, zx, rms_w + (size_t)l * DI, y2);
        gemmo_k<<<512, 256, 0, stream>>>(
            y2, obfAll + (size_t)l * DM * DI, res);
    }

    ln_k<float><<<TOK, 256, 0, stream>>>(res, norm_w, norm_b, (float*)d_out);
}

// Round 20
// 887.991 us; speedup vs baseline: 1.0726x; 1.0406x over previous
//
#include <hip/hip_runtime.h>
#include <stdint.h>

typedef unsigned short u16;
using bf16x8 = __attribute__((ext_vector_type(8))) short;
using f32x4  = __attribute__((ext_vector_type(4))) float;

#define BATCH 2
#define SEQ   2048
#define TOK   (BATCH*SEQ)      // 4096 tokens
#define DM    1024
#define NLAY  4
#define DI    2048
#define DSTT  64               // state dim DS
#define NH    32               // heads
#define HP    64               // head dim P
#define KC    4                // conv kernel
#define CHK   64               // chunk len
#define NC    (SEQ/CHK)        // 32 chunks
#define DCONV (DI + 2*DSTT)    // 2176
#define DINR  (2*DI + 2*DSTT + NH) // 4256
#define DINP  4352             // padded to 128 multiple
#define HPB   4                // heads per ydiagm block

#define MFMA16 __builtin_amdgcn_mfma_f32_16x16x32_bf16

__device__ __forceinline__ float b2f(u16 u) {
    union { uint32_t i; float f; } v; v.i = ((uint32_t)u) << 16; return v.f;
}
__device__ __forceinline__ u16 f2b(float f) {
    union { float f; uint32_t i; } v; v.f = f;
    uint32_t x = v.i;
    uint32_t r = x + 0x7fffu + ((x >> 16) & 1u);
    return (u16)(r >> 16);
}
__device__ __forceinline__ void gload16(const u16* g, u16* l) {
    __builtin_amdgcn_global_load_lds(
        (const __attribute__((address_space(1))) void*)g,
        (__attribute__((address_space(3))) void*)l, 16, 0, 0);
}
// ---- 64x64 bf16 operand tiles: [2 k-tiles][64 rows][32 cols], gemm swizzle --
__device__ __forceinline__ int swzb(int byo) {
    return byo ^ (((byo >> 6) & 7) << 4);
}
__device__ __forceinline__ void st16(u16* base, int r, int k, u16 v) {
    int byo = ((k >> 5) << 12) | ((r * 32 + (k & 31)) << 1);
    *(u16*)((char*)base + swzb(byo)) = v;
}
__device__ __forceinline__ void st32(u16* base, int r, int k, uint32_t v) {
    int byo = ((k >> 5) << 12) | ((r * 32 + (k & 31)) << 1);   // k even
    *(uint32_t*)((char*)base + swzb(byo)) = v;
}
__device__ __forceinline__ bf16x8 ldfrag(const u16* base, int rbase, int kt, int lane) {
    int byo = (kt << 12) | (((rbase + (lane & 15)) * 32 + ((lane >> 4) << 3)) << 1);
    return *(const bf16x8*)((const char*)base + swzb(byo));
}

// ---------------- embedding gather: res[t,:] = emb[ids[t],:] (f32) ----------
__global__ __launch_bounds__(256) void embed_k(const int* __restrict__ ids,
                                               const float* __restrict__ emb,
                                               float* __restrict__ res) {
    int t = blockIdx.x, tid = threadIdx.x;
    int id = ids[t];
    const float* er = emb + (size_t)id * DM;
    int i0 = tid * 4;
    *(float4*)(res + (size_t)t * DM + i0) = *(const float4*)(er + i0);
}

// ---------------- layernorm over DM: src f32 -> dst (bf16 or f32) -----------
template <typename OutT>
__global__ __launch_bounds__(256) void ln_k(const float* __restrict__ src,
                                            const float* __restrict__ w,
                                            const float* __restrict__ bb,
                                            OutT* __restrict__ dst) {
    __shared__ float r1[4], r2[4];
    int t = blockIdx.x, tid = threadIdx.x;
    const float* x = src + (size_t)t * DM;
    int i0 = tid * 4;
    float4 v = *(const float4*)(x + i0);
    float s1 = v.x + v.y + v.z + v.w;
    float s2 = v.x * v.x + v.y * v.y + v.z * v.z + v.w * v.w;
#pragma unroll
    for (int off = 32; off; off >>= 1) {
        s1 += __shfl_down(s1, off);
        s2 += __shfl_down(s2, off);
    }
    if ((tid & 63) == 0) { r1[tid >> 6] = s1; r2[tid >> 6] = s2; }
    __syncthreads();
    float S1 = r1[0] + r1[1] + r1[2] + r1[3];
    float S2 = r2[0] + r2[1] + r2[2] + r2[3];
    float mean = S1 * (1.f / DM);
    float var = S2 * (1.f / DM) - mean * mean;
    float inv = rsqrtf(var + 1e-5f);
    float4 wv = *(const float4*)(w + i0);
    float4 bv = *(const float4*)(bb + i0);
    OutT* d = dst + (size_t)t * DM + i0;
    float o0 = (v.x - mean) * inv * wv.x + bv.x;
    float o1 = (v.y - mean) * inv * wv.y + bv.y;
    float o2 = (v.z - mean) * inv * wv.z + bv.z;
    float o3 = (v.w - mean) * inv * wv.w + bv.w;
    if constexpr (sizeof(OutT) == 2) {
        d[0] = f2b(o0); d[1] = f2b(o1); d[2] = f2b(o2); d[3] = f2b(o3);
    } else {
        float4 o; o.x = o0; o.y = o1; o.z = o2; o.w = o3;
        *(float4*)d = o;
    }
}

// ------- pad+convert ALL layers in_w (f32) -> wpadAll (bf16, 4x4352x1024) ---
__global__ __launch_bounds__(256) void padw4_k(const float* __restrict__ w,
                                               u16* __restrict__ wp) {
    int idx = (blockIdx.x * 256 + threadIdx.x) * 4;
    int l = idx / (DINP * DM);
    int rem = idx - l * (DINP * DM);
    u16* dst = wp + (size_t)l * DINP * DM + rem;
    if (rem < DINR * DM) {
        float4 v = *(const float4*)(w + (size_t)l * DINR * DM + rem);
        dst[0] = f2b(v.x); dst[1] = f2b(v.y);
        dst[2] = f2b(v.z); dst[3] = f2b(v.w);
    } else {
        dst[0] = 0; dst[1] = 0; dst[2] = 0; dst[3] = 0;
    }
}

// ------- convert ALL layers out_w (f32) -> obfAll (bf16, 4x1024x2048) -------
__global__ __launch_bounds__(256) void cvt4_k(const float* __restrict__ src,
                                              u16* __restrict__ dst) {
    int idx = (blockIdx.x * 256 + threadIdx.x) * 4;
    float4 v = *(const float4*)(src + idx);
    dst[idx + 0] = f2b(v.x); dst[idx + 1] = f2b(v.y);
    dst[idx + 2] = f2b(v.z); dst[idx + 3] = f2b(v.w);
}

// ---------------- bf16 GEMM (m97 structure): C[m,n] = sum_k A[m,k]*B[n,k] ---
// Used only as gemm_k<0,1> (in-proj, bf16 LDS-coalesced store) — proven form.
template <int EPI, int KSPLIT>
__global__ __launch_bounds__(256) void gemm_k(const u16* __restrict__ A,
                                              const u16* __restrict__ Bw,
                                              u16* __restrict__ Cb,
                                              float* __restrict__ Cf,
                                              int N, int Kd, int ldc) {
    __shared__ u16 sm[8192];          // As = sm[0:4096], Bs = sm[4096:8192]
    u16* As = sm;
    u16* Bs = sm + 4096;
    const int tid = threadIdx.x;
    const int lane = tid & 63;
    const int w = tid >> 6;
    const int wm = w >> 1, wn = w & 1;
    const int nb = N >> 7;

    const int rowsPer = (gridDim.x / nb) >> 3;
    const int xcd = blockIdx.x & 7;
    const int local = blockIdx.x >> 3;
    const int bx = local / rowsPer;
    const int by = xcd * rowsPer + (local % rowsPer);
    const int row0 = by << 7, col0 = bx << 7;

    const int Kslice = Kd / KSPLIT;
    const int kbase = blockIdx.y * Kslice;

    const int srow = lane >> 2;
    const int skp  = (lane & 3) << 3;

    f32x4 zero = {0.f, 0.f, 0.f, 0.f};
    f32x4 acc[4][4];
#pragma unroll
    for (int i = 0; i < 4; i++)
#pragma unroll
        for (int j = 0; j < 4; j++) acc[i][j] = zero;

    const int tiles = Kslice >> 5;
    for (int kt = 0; kt < tiles; ++kt) {
        const int k0 = kbase + (kt << 5);
#pragma unroll
        for (int j = 0; j < 2; ++j) {
            int r = w * 32 + j * 16 + srow;
            gload16(A + (size_t)(row0 + r) * Kd + k0 + skp,
                    As + w * 1024 + j * 512);
            gload16(Bw + (size_t)(col0 + r) * Kd + k0 + skp,
                    Bs + w * 1024 + j * 512);
        }
        __syncthreads();
        bf16x8 af[4], bfr[4];
#pragma unroll
        for (int mi = 0; mi < 4; mi++) {
            int row = wm * 64 + mi * 16 + (lane & 15);
            af[mi] = *(const bf16x8*)(As + row * 32 + ((lane >> 4) << 3));
        }
#pragma unroll
        for (int ni = 0; ni < 4; ni++) {
            int row = wn * 64 + ni * 16 + (lane & 15);
            bfr[ni] = *(const bf16x8*)(Bs + row * 32 + ((lane >> 4) << 3));
        }
#pragma unroll
        for (int mi = 0; mi < 4; mi++)
#pragma unroll
            for (int ni = 0; ni < 4; ni++)
                acc[mi][ni] = MFMA16(af[mi], bfr[ni], acc[mi][ni], 0, 0, 0);
        __syncthreads();
    }

    if (EPI == 0) {
#pragma unroll
        for (int half = 0; half < 2; ++half) {
            if (wm == half) {
#pragma unroll
                for (int mi = 0; mi < 4; mi++)
#pragma unroll
                    for (int ni = 0; ni < 4; ni++) {
                        int lr = mi * 16 + ((lane >> 4) << 2);
                        int col = wn * 64 + ni * 16 + (lane & 15);
#pragma unroll
                        for (int rr = 0; rr < 4; rr++)
                            sm[(lr + rr) * 128 + col] = f2b(acc[mi][ni][rr]);
                    }
            }
            __syncthreads();
#pragma unroll
            for (int q = 0; q < 4; q++) {
                int lr = w * 16 + q * 4 + (lane >> 4);
                int colb = (lane & 15) * 16;
                int4 v = *(const int4*)((const char*)sm + lr * 256 + colb);
                char* gp = (char*)(Cb + (size_t)(row0 + half * 64 + lr) * ldc + col0) + colb;
                *(int4*)gp = v;
            }
            __syncthreads();
        }
    } else {
#pragma unroll
        for (int mi = 0; mi < 4; mi++)
#pragma unroll
            for (int ni = 0; ni < 4; ni++) {
                int mbase = row0 + wm * 64 + mi * 16 + ((lane >> 4) << 2);
                int n = col0 + wn * 64 + ni * 16 + (lane & 15);
#pragma unroll
                for (int rr = 0; rr < 4; rr++) {
                    size_t off = (size_t)(mbase + rr) * ldc + n;
                    if (KSPLIT == 1) Cf[off] += acc[mi][ni][rr];
                    else atomicAdd(Cf + off, acc[mi][ni][rr]);
                }
            }
    }
}

// ---------------- out-proj GEMM: res[m,n] += sum_k y2[m,k]*obf[n,k] ---------
// 128x64 tile, 512 blocks, KSPLIT=1, deterministic += (no atomics).
__global__ __launch_bounds__(256) void gemmo_k(const u16* __restrict__ A,
                                               const u16* __restrict__ Bw,
                                               float* __restrict__ Cf) {
    __shared__ u16 As[128 * 32];      // 8 KB
    __shared__ u16 Bs[64 * 32];       // 4 KB
    const int tid = threadIdx.x;
    const int lane = tid & 63;
    const int w = tid >> 6;
    const int wm = w >> 1, wn = w & 1;

    const int rowsPer = 4;
    const int xcd = blockIdx.x & 7;
    const int local = blockIdx.x >> 3;
    const int bx = local / rowsPer;
    const int by = xcd * rowsPer + (local % rowsPer);
    const int row0 = by << 7, col0 = bx << 6;

    const int srow = lane >> 2;          // 0..15
    const int skp  = (lane & 3) << 3;    // 0,8,16,24

    f32x4 zero = {0.f, 0.f, 0.f, 0.f};
    f32x4 acc[4][2];
#pragma unroll
    for (int i = 0; i < 4; i++)
#pragma unroll
        for (int j = 0; j < 2; j++) acc[i][j] = zero;

    const int tiles = DI >> 5;           // 64
    for (int kt = 0; kt < tiles; ++kt) {
        const int k0 = kt << 5;
#pragma unroll
        for (int j = 0; j < 2; ++j) {
            int r = w * 32 + j * 16 + srow;
            gload16(A + (size_t)(row0 + r) * DI + k0 + skp,
                    As + w * 1024 + j * 512);
        }
        {
            int r = w * 16 + srow;
            gload16(Bw + (size_t)(col0 + r) * DI + k0 + skp,
                    Bs + w * 512);
        }
        __syncthreads();
        bf16x8 af[4], bfr[2];
#pragma unroll
        for (int mi = 0; mi < 4; mi++) {
            int row = wm * 64 + mi * 16 + (lane & 15);
            af[mi] = *(const bf16x8*)(As + row * 32 + ((lane >> 4) << 3));
        }
#pragma unroll
        for (int ni = 0; ni < 2; ni++) {
            int row = wn * 32 + ni * 16 + (lane & 15);
            bfr[ni] = *(const bf16x8*)(Bs + row * 32 + ((lane >> 4) << 3));
        }
#pragma unroll
        for (int mi = 0; mi < 4; mi++)
#pragma unroll
            for (int ni = 0; ni < 2; ni++)
                acc[mi][ni] = MFMA16(af[mi], bfr[ni], acc[mi][ni], 0, 0, 0);
        __syncthreads();
    }

#pragma unroll
    for (int mi = 0; mi < 4; mi++)
#pragma unroll
        for (int ni = 0; ni < 2; ni++) {
            int mbase = row0 + wm * 64 + mi * 16 + ((lane >> 4) << 2);
            int n = col0 + wn * 32 + ni * 16 + (lane & 15);
#pragma unroll
            for (int rr = 0; rr < 4; rr++) {
                size_t off = (size_t)(mbase + rr) * DM + n;
                Cf[off] += acc[mi][ni][rr];
            }
        }
}

// ---------------- causal conv1d (K=4) + bias + SiLU, x4 vectorized ----------
// thread -> (t, 4-channel group); exact grid TOK*DCONV/4/256 = 8704 blocks
__global__ __launch_bounds__(256) void conv_k(const u16* __restrict__ zx,
                                              const float* __restrict__ cw,
                                              const float* __restrict__ cb,
                                              u16* __restrict__ xbc) {
    int idx = blockIdx.x * 256 + threadIdx.x;
    int c0 = (idx % (DCONV / 4)) * 4;
    int t  = idx / (DCONV / 4);
    int s = t % SEQ;
    float a0 = cb[c0 + 0], a1 = cb[c0 + 1], a2 = cb[c0 + 2], a3 = cb[c0 + 3];
    float4 w0 = *(const float4*)(cw + (c0 + 0) * KC);
    float4 w1 = *(const float4*)(cw + (c0 + 1) * KC);
    float4 w2 = *(const float4*)(cw + (c0 + 2) * KC);
    float4 w3 = *(const float4*)(cw + (c0 + 3) * KC);
#pragma unroll
    for (int k = 0; k < KC; k++) {
        int ss = s - 3 + k;
        if (ss >= 0) {
            ushort4 v = *(const ushort4*)(zx + (size_t)(t - 3 + k) * DINP + DI + c0);
            float tap0 = (k == 0) ? w0.x : (k == 1) ? w0.y : (k == 2) ? w0.z : w0.w;
            float tap1 = (k == 0) ? w1.x : (k == 1) ? w1.y : (k == 2) ? w1.z : w1.w;
            float tap2 = (k == 0) ? w2.x : (k == 1) ? w2.y : (k == 2) ? w2.z : w2.w;
            float tap3 = (k == 0) ? w3.x : (k == 1) ? w3.y : (k == 2) ? w3.z : w3.w;
            a0 += tap0 * b2f(v.x);
            a1 += tap1 * b2f(v.y);
            a2 += tap2 * b2f(v.z);
            a3 += tap3 * b2f(v.w);
        }
    }
    a0 = a0 / (1.f + __expf(-a0));
    a1 = a1 / (1.f + __expf(-a1));
    a2 = a2 / (1.f + __expf(-a2));
    a3 = a3 / (1.f + __expf(-a3));
    ushort4 o;
    o.x = f2b(a0); o.y = f2b(a1); o.z = f2b(a2); o.w = f2b(a3);
    *(ushort4*)(xbc + (size_t)t * DCONV + c0) = o;
}

// ---------------- dt/acum: LDS-staged parallel load + fast cumsum -----------
// block = b*NC + c ; 256 threads
__global__ __launch_bounds__(256) void dtacum_k(const u16* __restrict__ zx,
                                                const float* __restrict__ dtb,
                                                const float* __restrict__ alog,
                                                float* __restrict__ dt,
                                                float* __restrict__ acum) {
    __shared__ float raw[64][33], dts[64][33], acs[64][33];
    int bc = blockIdx.x;
    int t0 = bc * CHK;
    int tid = threadIdx.x;
#pragma unroll
    for (int it = 0; it < 8; ++it) {
        int idx = it * 256 + tid;
        int l = idx >> 5, h = idx & 31;
        raw[l][h] = b2f(zx[(size_t)(t0 + l) * DINP + DI + DCONV + h]);
    }
    __syncthreads();
    if (tid < NH) {
        int h = tid;
        float bias = dtb[h];
        float Ah = -__expf(alog[h]);
        float run = 0.f;
#pragma unroll 4
        for (int l = 0; l < CHK; l++) {
            float x = raw[l][h] + bias;
            float d = (x > 20.f) ? x : log1pf(__expf(x));
            dts[l][h] = d;
            run += d * Ah;
            acs[l][h] = run;
        }
    }
    __syncthreads();
#pragma unroll
    for (int it = 0; it < 8; ++it) {
        int idx = it * 256 + tid;
        int l = idx >> 5, h = idx & 31;
        dt[(size_t)(t0 + l) * NH + h] = dts[l][h];
        acum[(size_t)(t0 + l) * NH + h] = acs[l][h];
    }
}

// ---------------- intra-chunk via MFMA (exp-factorized), bf16 yb ------------
// block = (b*NC+c)*(NH/HPB) + hg ; heads h = hg*HPB + 0..HPB-1
__global__ __launch_bounds__(256) void ydiagm_k(const u16* __restrict__ xbc,
                                                const float* __restrict__ dt_,
                                                const float* __restrict__ acum,
                                                const float* __restrict__ Dw,
                                                u16* __restrict__ yb,
                                                float* __restrict__ st) {
    __shared__ u16 Bl[8192/2], Cl[8192/2], BlT[8192/2], CBm[8192/2], XpT[8192/2];
    __shared__ float cs[2][64], rs[2][64];
    const int tid = threadIdx.x;
    const int lane = tid & 63;
    const int w = tid >> 6;
    const int blk = blockIdx.x;
    const int hg = blk & (NH / HPB - 1);
    const int bc = blk / (NH / HPB);
    const int t0 = bc * CHK;

    for (int it = 0; it < 8; ++it) {
        int idx2 = it * 256 + tid;
        int r = idx2 >> 5;
        int j0 = (idx2 & 31) * 2;
        size_t rowp = (size_t)(t0 + r) * DCONV;
        uint32_t bv = *(const uint32_t*)(xbc + rowp + DI + j0);
        uint32_t cv = *(const uint32_t*)(xbc + rowp + DI + DSTT + j0);
        st32(Bl, r, j0, bv);
        st32(Cl, r, j0, cv);
        st16(BlT, j0, r, (u16)(bv & 0xffff));
        st16(BlT, j0 + 1, r, (u16)(bv >> 16));
    }
    {
        int4 z4 = {0, 0, 0, 0};
        *(int4*)((char*)CBm + tid * 16) = z4;
        *(int4*)((char*)CBm + 4096 + tid * 16) = z4;
    }
    if (tid < 64) {
        int h0 = hg * HPB;
        float a = acum[(size_t)(t0 + tid) * NH + h0];
        float d = dt_[(size_t)(t0 + tid) * NH + h0];
        cs[0][tid] = __expf(-a) * d;
        rs[0][tid] = __expf(a);
    }
    __syncthreads();

    {
        bf16x8 a0 = ldfrag(Cl, w * 16, 0, lane);
        bf16x8 a1 = ldfrag(Cl, w * 16, 1, lane);
        for (int stt = 0; stt <= w; ++stt) {
            f32x4 acc = {0.f, 0.f, 0.f, 0.f};
            acc = MFMA16(a0, ldfrag(Bl, stt * 16, 0, lane), acc, 0, 0, 0);
            acc = MFMA16(a1, ldfrag(Bl, stt * 16, 1, lane), acc, 0, 0, 0);
            int lrow = w * 16 + ((lane >> 4) << 2);
            int scol = stt * 16 + (lane & 15);
#pragma unroll
            for (int rr = 0; rr < 4; rr++) {
                int lg = lrow + rr;
                u16 v = (scol <= lg) ? f2b(acc[rr]) : (u16)0;
                st16(CBm, lg, scol, v);
            }
        }
    }

    int cur = 0;
    for (int hh = 0; hh < HPB; ++hh) {
        const int h = hg * HPB + hh;
        const int nxt = cur ^ 1;
        for (int it = 0; it < 8; ++it) {
            int s0 = it * 8 + w * 2;
            float c0 = cs[cur][s0], c1 = cs[cur][s0 + 1];
            float x0 = b2f(xbc[(size_t)(t0 + s0) * DCONV + h * HP + lane]);
            float x1 = b2f(xbc[(size_t)(t0 + s0 + 1) * DCONV + h * HP + lane]);
            uint32_t pk = (uint32_t)f2b(c0 * x0) | ((uint32_t)f2b(c1 * x1) << 16);
            st32(XpT, lane, s0, pk);
        }
        if (hh < HPB - 1 && tid < 64) {
            float a = acum[(size_t)(t0 + tid) * NH + h + 1];
            float d = dt_[(size_t)(t0 + tid) * NH + h + 1];
            cs[nxt][tid] = __expf(-a) * d;
            rs[nxt][tid] = __expf(a);
        }
        __syncthreads();

        {
            float Dh = Dw[h];
#pragma unroll
            for (int nt = 0; nt < 4; ++nt) {
                f32x4 acc = {0.f, 0.f, 0.f, 0.f};
                acc = MFMA16(ldfrag(CBm, w * 16, 0, lane),
                             ldfrag(XpT, nt * 16, 0, lane), acc, 0, 0, 0);
                if (w >= 2)
                    acc = MFMA16(ldfrag(CBm, w * 16, 1, lane),
                                 ldfrag(XpT, nt * 16, 1, lane), acc, 0, 0, 0);
                int lrow = w * 16 + ((lane >> 4) << 2);
                int pg = nt * 16 + (lane & 15);
#pragma unroll
                for (int rr = 0; rr < 4; rr++) {
                    int lg = lrow + rr;
                    float xr = b2f(xbc[(size_t)(t0 + lg) * DCONV + h * HP + pg]);
                    yb[(size_t)(t0 + lg) * DI + h * HP + pg] =
                        f2b(rs[cur][lg] * acc[rr] + Dh * xr);
                }
            }
        }
        {
            float dcv = rs[cur][63];
            float* so = st + (size_t)(bc * NH + h) * (HP * DSTT);
            bf16x8 a0 = ldfrag(XpT, w * 16, 0, lane);
            bf16x8 a1 = ldfrag(XpT, w * 16, 1, lane);
#pragma unroll
            for (int nt = 0; nt < 4; ++nt) {
                f32x4 acc = {0.f, 0.f, 0.f, 0.f};
                acc = MFMA16(a0, ldfrag(BlT, nt * 16, 0, lane), acc, 0, 0, 0);
                acc = MFMA16(a1, ldfrag(BlT, nt * 16, 1, lane), acc, 0, 0, 0);
                int prow = w * 16 + ((lane >> 4) << 2);
                int ng = nt * 16 + (lane & 15);
#pragma unroll
                for (int rr = 0; rr < 4; rr++)
                    so[(size_t)(prow + rr) * DSTT + ng] = dcv * acc[rr];
            }
        }
        __syncthreads();
        cur ^= 1;
    }
}

// ---------------- element-parallel inter-chunk scan (in place) --------------
__global__ __launch_bounds__(256) void chainscan_k(const float* __restrict__ acum,
                                                   float* __restrict__ st) {
    __shared__ float dc[NC];
    int blk = blockIdx.x;
    int slice = blk & 15;
    int bh = blk >> 4;
    int h = bh % NH, b = bh / NH;
    int tid = threadIdx.x;
    if (tid < NC)
        dc[tid] = __expf(acum[(size_t)(b * SEQ + tid * CHK + CHK - 1) * NH + h]);
    __syncthreads();
    int e = slice * 256 + tid;
    float* p = st + ((size_t)(b * NC) * NH + h) * (HP * DSTT) + e;
    const size_t cstride = (size_t)NH * HP * DSTT;
    float s = 0.f;
#pragma unroll 4
    for (int c = 0; c < NC; c++) {
        float v = p[c * cstride];
        p[c * cstride] = s;
        s = dc[c] * s + v;
    }
}

// ---------------- y_off via MFMA: yb[l,p] += ea[l]*sum_n C[l,n]*S[p,n] ------
// block = (b*NC + c)*NH + h ; bf16 yb RMW
__global__ __launch_bounds__(256) void yoffm_k(const u16* __restrict__ xbc,
                                               const float* __restrict__ acum,
                                               const float* __restrict__ S,
                                               u16* __restrict__ yb) {
    __shared__ u16 Cl[4096], Sl[4096];   // two 64x64 bf16 tiles
    __shared__ float eal[64];
    const int blk = blockIdx.x;
    const int h = blk % NH;
    const int bc = blk / NH;
    const int t0 = bc * CHK;
    const int tid = threadIdx.x;
    const int lane = tid & 63;
    const int w = tid >> 6;

    for (int it = 0; it < 8; ++it) {
        int idx2 = it * 256 + tid;
        int r = idx2 >> 5;              // 0..63
        int j0 = (idx2 & 31) * 2;       // 0..62 even
        uint32_t cv = *(const uint32_t*)(xbc + (size_t)(t0 + r) * DCONV + DI + DSTT + j0);
        st32(Cl, r, j0, cv);
    }
    const float* Sp = S + (size_t)blk * (HP * DSTT);
    for (int it = 0; it < 8; ++it) {
        int idx2 = it * 256 + tid;
        int p = idx2 >> 5;
        int j0 = (idx2 & 31) * 2;
        float s0 = Sp[p * DSTT + j0];
        float s1 = Sp[p * DSTT + j0 + 1];
        st32(Sl, p, j0, (uint32_t)f2b(s0) | ((uint32_t)f2b(s1) << 16));
    }
    if (tid < 64) eal[tid] = __expf(acum[(size_t)(t0 + tid) * NH + h]);
    __syncthreads();

    bf16x8 a0 = ldfrag(Cl, w * 16, 0, lane);
    bf16x8 a1 = ldfrag(Cl, w * 16, 1, lane);
#pragma unroll
    for (int nt = 0; nt < 4; ++nt) {
        f32x4 acc = {0.f, 0.f, 0.f, 0.f};
        acc = MFMA16(a0, ldfrag(Sl, nt * 16, 0, lane), acc, 0, 0, 0);
        acc = MFMA16(a1, ldfrag(Sl, nt * 16, 1, lane), acc, 0, 0, 0);
        int lrow = w * 16 + ((lane >> 4) << 2);
        int pg = nt * 16 + (lane & 15);
#pragma unroll
        for (int rr = 0; rr < 4; rr++) {
            int lg = lrow + rr;
            u16* yp = yb + (size_t)(t0 + lg) * DI + h * HP + pg;
            *yp = f2b(b2f(*yp) + eal[lg] * acc[rr]);
        }
    }
}

// ---------------- gate (y * silu(z)) + RMSNorm * rms_w -> bf16 --------------
__global__ __launch_bounds__(256) void gaterms_k(const u16* __restrict__ yb,
                                                 const u16* __restrict__ zx,
                                                 const float* __restrict__ rw,
                                                 u16* __restrict__ y2) {
    __shared__ float red[4];
    int t = blockIdx.x, tid = threadIdx.x;
    const u16* yr = yb + (size_t)t * DI;
    const u16* zr = zx + (size_t)t * DINP;
    int i0 = tid * 8;
    int4 yv4 = *(const int4*)(yr + i0);
    int4 zv4 = *(const int4*)(zr + i0);
    const u16* yp = (const u16*)&yv4;
    const u16* zp = (const u16*)&zv4;
    float g[8];
    float ss = 0.f;
#pragma unroll
    for (int j = 0; j < 8; j++) {
        float y = b2f(yp[j]);
        float z = b2f(zp[j]);
        float sl = z / (1.f + __expf(-z));
        float v = y * sl;
        g[j] = v;
        ss += v * v;
    }
#pragma unroll
    for (int off = 32; off; off >>= 1) ss += __shfl_down(ss, off);
    if ((tid & 63) == 0) red[tid >> 6] = ss;
    __syncthreads();
    float tot = red[0] + red[1] + red[2] + red[3];
    float sc = rsqrtf(tot * (1.f / DI) + 1e-5f);
    u16* yo = y2 + (size_t)t * DI + i0;
#pragma unroll
    for (int j = 0; j < 8; j++) yo[j] = f2b(g[j] * sc * rw[i0 + j]);
}

// ============================ host-side launch ==============================
extern "C" void kernel_launch(void* const* d_in, const int* in_sizes, int n_in,
                              void* d_out, int out_size, void* d_ws, size_t ws_size,
                              hipStream_t stream) {
    const int*   ids      = (const int*)d_in[0];
    const float* emb      = (const float*)d_in[2];
    const float* ln_w     = (const float*)d_in[3];
    const float* ln_b     = (const float*)d_in[4];
    const float* in_w     = (const float*)d_in[5];
    const float* conv_w   = (const float*)d_in[6];
    const float* conv_b   = (const float*)d_in[7];
    const float* dt_bias  = (const float*)d_in[8];
    const float* A_log    = (const float*)d_in[9];
    const float* Dw       = (const float*)d_in[10];
    const float* rms_w    = (const float*)d_in[11];
    const float* out_w    = (const float*)d_in[12];
    const float* norm_w   = (const float*)d_in[13];
    const float* norm_b   = (const float*)d_in[14];

    char* ws = (char*)d_ws;
    float* res    = (float*)(ws);                  // 16,777,216 B
    u16*   zx     = (u16*)  (ws + 16777216);       // 35,651,584 B (stride DINP)
    u16*   xbc    = (u16*)  (ws + 52428800);       // 17,825,792 B
    float* dt     = (float*)(ws + 70254592);       //    524,288 B
    float* acum   = (float*)(ws + 70778880);       //    524,288 B
    u16*   yb     = (u16*)  (ws + 71303168);       // 16,777,216 B (bf16 now)
    u16*   h      = (u16*)  (ws + 88080384);       //  8,388,608 B (no alias)
    float* st     = (float*)(ws + 104857600);      // 33,554,432 B
    u16*   y2     = (u16*)  (ws + 138412032);      // 16,777,216 B
    u16*   wpadAll= (u16*)  (ws + 155189248);      // 35,651,584 B (4 layers)
    u16*   obfAll = (u16*)  (ws + 190840832);      // 16,777,216 B (4 layers)
    const size_t NEED = 207618048;
    if (ws_size < NEED) return;

    // one-shot weight conversions (all layers)
    padw4_k<<<NLAY * DINP * DM / 4 / 256, 256, 0, stream>>>(in_w, wpadAll);
    cvt4_k<<<NLAY * DM * DI / 4 / 256, 256, 0, stream>>>(out_w, obfAll);

    embed_k<<<TOK, 256, 0, stream>>>(ids, emb, res);

    for (int l = 0; l < NLAY; ++l) {
        ln_k<u16><<<TOK, 256, 0, stream>>>(res, ln_w + l * DM, ln_b + l * DM, h);
        gemm_k<0, 1><<<(TOK / 128) * (DINP / 128), 256, 0, stream>>>(
            h, wpadAll + (size_t)l * DINP * DM, zx, nullptr, DINP, DM, DINP);
        conv_k<<<TOK * DCONV / 4 / 256, 256, 0, stream>>>(
            zx, conv_w + (size_t)l * DCONV * KC, conv_b + (size_t)l * DCONV, xbc);
        dtacum_k<<<BATCH * NC, 256, 0, stream>>>(
            zx, dt_bias + l * NH, A_log + l * NH, dt, acum);
        ydiagm_k<<<BATCH * NC * (NH / HPB), 256, 0, stream>>>(
            xbc, dt, acum, Dw + l * NH, yb, st);
        chainscan_k<<<BATCH * NH * 16, 256, 0, stream>>>(acum, st);
        yoffm_k<<<BATCH * NC * NH, 256, 0, stream>>>(xbc, acum, st, yb);
        gaterms_k<<<TOK, 256, 0, stream>>>(yb, zx, rms_w + (size_t)l * DI, y2);
        gemmo_k<<<512, 256, 0, stream>>>(
            y2, obfAll + (size_t)l * DM * DI, res);
    }

    ln_k<float><<<TOK, 256, 0, stream>>>(res, norm_w, norm_b, (float*)d_out);
}

// Round 21
// 859.584 us; speedup vs baseline: 1.1081x; 1.0330x over previous
//
#include <hip/hip_runtime.h>
#include <stdint.h>

typedef unsigned short u16;
using bf16x8 = __attribute__((ext_vector_type(8))) short;
using f32x4  = __attribute__((ext_vector_type(4))) float;

#define BATCH 2
#define SEQ   2048
#define TOK   (BATCH*SEQ)      // 4096 tokens
#define DM    1024
#define NLAY  4
#define DI    2048
#define DSTT  64               // state dim DS
#define NH    32               // heads
#define HP    64               // head dim P
#define KC    4                // conv kernel
#define CHK   64               // chunk len
#define NC    (SEQ/CHK)        // 32 chunks
#define DCONV (DI + 2*DSTT)    // 2176
#define DINR  (2*DI + 2*DSTT + NH) // 4256
#define DINP  4352             // padded to 128 multiple
#define HPB   4                // heads per ydiagm block

#define MFMA16 __builtin_amdgcn_mfma_f32_16x16x32_bf16

__device__ __forceinline__ float b2f(u16 u) {
    union { uint32_t i; float f; } v; v.i = ((uint32_t)u) << 16; return v.f;
}
__device__ __forceinline__ u16 f2b(float f) {
    union { float f; uint32_t i; } v; v.f = f;
    uint32_t x = v.i;
    uint32_t r = x + 0x7fffu + ((x >> 16) & 1u);
    return (u16)(r >> 16);
}
__device__ __forceinline__ void gload16(const u16* g, u16* l) {
    __builtin_amdgcn_global_load_lds(
        (const __attribute__((address_space(1))) void*)g,
        (__attribute__((address_space(3))) void*)l, 16, 0, 0);
}
// ---- 64x64 bf16 operand tiles: [2 k-tiles][64 rows][32 cols], gemm swizzle --
__device__ __forceinline__ int swzb(int byo) {
    return byo ^ (((byo >> 6) & 7) << 4);
}
__device__ __forceinline__ void st16(u16* base, int r, int k, u16 v) {
    int byo = ((k >> 5) << 12) | ((r * 32 + (k & 31)) << 1);
    *(u16*)((char*)base + swzb(byo)) = v;
}
__device__ __forceinline__ void st32(u16* base, int r, int k, uint32_t v) {
    int byo = ((k >> 5) << 12) | ((r * 32 + (k & 31)) << 1);   // k even
    *(uint32_t*)((char*)base + swzb(byo)) = v;
}
__device__ __forceinline__ bf16x8 ldfrag(const u16* base, int rbase, int kt, int lane) {
    int byo = (kt << 12) | (((rbase + (lane & 15)) * 32 + ((lane >> 4) << 3)) << 1);
    return *(const bf16x8*)((const char*)base + swzb(byo));
}

// ---------------- embedding gather: res[t,:] = emb[ids[t],:] (f32) ----------
__global__ __launch_bounds__(256) void embed_k(const int* __restrict__ ids,
                                               const float* __restrict__ emb,
                                               float* __restrict__ res) {
    int t = blockIdx.x, tid = threadIdx.x;
    int id = ids[t];
    const float* er = emb + (size_t)id * DM;
    int i0 = tid * 4;
    *(float4*)(res + (size_t)t * DM + i0) = *(const float4*)(er + i0);
}

// ---------------- layernorm over DM: src f32 -> dst (bf16 or f32) -----------
template <typename OutT>
__global__ __launch_bounds__(256) void ln_k(const float* __restrict__ src,
                                            const float* __restrict__ w,
                                            const float* __restrict__ bb,
                                            OutT* __restrict__ dst) {
    __shared__ float r1[4], r2[4];
    int t = blockIdx.x, tid = threadIdx.x;
    const float* x = src + (size_t)t * DM;
    int i0 = tid * 4;
    float4 v = *(const float4*)(x + i0);
    float s1 = v.x + v.y + v.z + v.w;
    float s2 = v.x * v.x + v.y * v.y + v.z * v.z + v.w * v.w;
#pragma unroll
    for (int off = 32; off; off >>= 1) {
        s1 += __shfl_down(s1, off);
        s2 += __shfl_down(s2, off);
    }
    if ((tid & 63) == 0) { r1[tid >> 6] = s1; r2[tid >> 6] = s2; }
    __syncthreads();
    float S1 = r1[0] + r1[1] + r1[2] + r1[3];
    float S2 = r2[0] + r2[1] + r2[2] + r2[3];
    float mean = S1 * (1.f / DM);
    float var = S2 * (1.f / DM) - mean * mean;
    float inv = rsqrtf(var + 1e-5f);
    float4 wv = *(const float4*)(w + i0);
    float4 bv = *(const float4*)(bb + i0);
    OutT* d = dst + (size_t)t * DM + i0;
    float o0 = (v.x - mean) * inv * wv.x + bv.x;
    float o1 = (v.y - mean) * inv * wv.y + bv.y;
    float o2 = (v.z - mean) * inv * wv.z + bv.z;
    float o3 = (v.w - mean) * inv * wv.w + bv.w;
    if constexpr (sizeof(OutT) == 2) {
        d[0] = f2b(o0); d[1] = f2b(o1); d[2] = f2b(o2); d[3] = f2b(o3);
    } else {
        float4 o; o.x = o0; o.y = o1; o.z = o2; o.w = o3;
        *(float4*)d = o;
    }
}

// ------- pad+convert ALL layers in_w (f32) -> wpadAll (bf16, 4x4352x1024) ---
__global__ __launch_bounds__(256) void padw4_k(const float* __restrict__ w,
                                               u16* __restrict__ wp) {
    int idx = (blockIdx.x * 256 + threadIdx.x) * 4;
    int l = idx / (DINP * DM);
    int rem = idx - l * (DINP * DM);
    u16* dst = wp + (size_t)l * DINP * DM + rem;
    if (rem < DINR * DM) {
        float4 v = *(const float4*)(w + (size_t)l * DINR * DM + rem);
        dst[0] = f2b(v.x); dst[1] = f2b(v.y);
        dst[2] = f2b(v.z); dst[3] = f2b(v.w);
    } else {
        dst[0] = 0; dst[1] = 0; dst[2] = 0; dst[3] = 0;
    }
}

// ------- convert ALL layers out_w (f32) -> obfAll (bf16, 4x1024x2048) -------
__global__ __launch_bounds__(256) void cvt4_k(const float* __restrict__ src,
                                              u16* __restrict__ dst) {
    int idx = (blockIdx.x * 256 + threadIdx.x) * 4;
    float4 v = *(const float4*)(src + idx);
    dst[idx + 0] = f2b(v.x); dst[idx + 1] = f2b(v.y);
    dst[idx + 2] = f2b(v.z); dst[idx + 3] = f2b(v.w);
}

// ---------------- bf16 GEMM (m97 structure): C[m,n] = sum_k A[m,k]*B[n,k] ---
// Used only as gemm_k<0,1> (in-proj, bf16 LDS-coalesced store) — proven form.
template <int EPI, int KSPLIT>
__global__ __launch_bounds__(256) void gemm_k(const u16* __restrict__ A,
                                              const u16* __restrict__ Bw,
                                              u16* __restrict__ Cb,
                                              float* __restrict__ Cf,
                                              int N, int Kd, int ldc) {
    __shared__ u16 sm[8192];          // As = sm[0:4096], Bs = sm[4096:8192]
    u16* As = sm;
    u16* Bs = sm + 4096;
    const int tid = threadIdx.x;
    const int lane = tid & 63;
    const int w = tid >> 6;
    const int wm = w >> 1, wn = w & 1;
    const int nb = N >> 7;

    const int rowsPer = (gridDim.x / nb) >> 3;
    const int xcd = blockIdx.x & 7;
    const int local = blockIdx.x >> 3;
    const int bx = local / rowsPer;
    const int by = xcd * rowsPer + (local % rowsPer);
    const int row0 = by << 7, col0 = bx << 7;

    const int Kslice = Kd / KSPLIT;
    const int kbase = blockIdx.y * Kslice;

    const int srow = lane >> 2;
    const int skp  = (lane & 3) << 3;

    f32x4 zero = {0.f, 0.f, 0.f, 0.f};
    f32x4 acc[4][4];
#pragma unroll
    for (int i = 0; i < 4; i++)
#pragma unroll
        for (int j = 0; j < 4; j++) acc[i][j] = zero;

    const int tiles = Kslice >> 5;
    for (int kt = 0; kt < tiles; ++kt) {
        const int k0 = kbase + (kt << 5);
#pragma unroll
        for (int j = 0; j < 2; ++j) {
            int r = w * 32 + j * 16 + srow;
            gload16(A + (size_t)(row0 + r) * Kd + k0 + skp,
                    As + w * 1024 + j * 512);
            gload16(Bw + (size_t)(col0 + r) * Kd + k0 + skp,
                    Bs + w * 1024 + j * 512);
        }
        __syncthreads();
        bf16x8 af[4], bfr[4];
#pragma unroll
        for (int mi = 0; mi < 4; mi++) {
            int row = wm * 64 + mi * 16 + (lane & 15);
            af[mi] = *(const bf16x8*)(As + row * 32 + ((lane >> 4) << 3));
        }
#pragma unroll
        for (int ni = 0; ni < 4; ni++) {
            int row = wn * 64 + ni * 16 + (lane & 15);
            bfr[ni] = *(const bf16x8*)(Bs + row * 32 + ((lane >> 4) << 3));
        }
#pragma unroll
        for (int mi = 0; mi < 4; mi++)
#pragma unroll
            for (int ni = 0; ni < 4; ni++)
                acc[mi][ni] = MFMA16(af[mi], bfr[ni], acc[mi][ni], 0, 0, 0);
        __syncthreads();
    }

    if (EPI == 0) {
#pragma unroll
        for (int half = 0; half < 2; ++half) {
            if (wm == half) {
#pragma unroll
                for (int mi = 0; mi < 4; mi++)
#pragma unroll
                    for (int ni = 0; ni < 4; ni++) {
                        int lr = mi * 16 + ((lane >> 4) << 2);
                        int col = wn * 64 + ni * 16 + (lane & 15);
#pragma unroll
                        for (int rr = 0; rr < 4; rr++)
                            sm[(lr + rr) * 128 + col] = f2b(acc[mi][ni][rr]);
                    }
            }
            __syncthreads();
#pragma unroll
            for (int q = 0; q < 4; q++) {
                int lr = w * 16 + q * 4 + (lane >> 4);
                int colb = (lane & 15) * 16;
                int4 v = *(const int4*)((const char*)sm + lr * 256 + colb);
                char* gp = (char*)(Cb + (size_t)(row0 + half * 64 + lr) * ldc + col0) + colb;
                *(int4*)gp = v;
            }
            __syncthreads();
        }
    } else {
#pragma unroll
        for (int mi = 0; mi < 4; mi++)
#pragma unroll
            for (int ni = 0; ni < 4; ni++) {
                int mbase = row0 + wm * 64 + mi * 16 + ((lane >> 4) << 2);
                int n = col0 + wn * 64 + ni * 16 + (lane & 15);
#pragma unroll
                for (int rr = 0; rr < 4; rr++) {
                    size_t off = (size_t)(mbase + rr) * ldc + n;
                    if (KSPLIT == 1) Cf[off] += acc[mi][ni][rr];
                    else atomicAdd(Cf + off, acc[mi][ni][rr]);
                }
            }
    }
}

// ---------------- out-proj GEMM: res[m,n] += sum_k y2[m,k]*obf[n,k] ---------
// 128x64 tile, 512 blocks, KSPLIT=1, deterministic += (no atomics).
__global__ __launch_bounds__(256) void gemmo_k(const u16* __restrict__ A,
                                               const u16* __restrict__ Bw,
                                               float* __restrict__ Cf) {
    __shared__ u16 As[128 * 32];      // 8 KB
    __shared__ u16 Bs[64 * 32];       // 4 KB
    const int tid = threadIdx.x;
    const int lane = tid & 63;
    const int w = tid >> 6;
    const int wm = w >> 1, wn = w & 1;

    const int rowsPer = 4;
    const int xcd = blockIdx.x & 7;
    const int local = blockIdx.x >> 3;
    const int bx = local / rowsPer;
    const int by = xcd * rowsPer + (local % rowsPer);
    const int row0 = by << 7, col0 = bx << 6;

    const int srow = lane >> 2;          // 0..15
    const int skp  = (lane & 3) << 3;    // 0,8,16,24

    f32x4 zero = {0.f, 0.f, 0.f, 0.f};
    f32x4 acc[4][2];
#pragma unroll
    for (int i = 0; i < 4; i++)
#pragma unroll
        for (int j = 0; j < 2; j++) acc[i][j] = zero;

    const int tiles = DI >> 5;           // 64
    for (int kt = 0; kt < tiles; ++kt) {
        const int k0 = kt << 5;
#pragma unroll
        for (int j = 0; j < 2; ++j) {
            int r = w * 32 + j * 16 + srow;
            gload16(A + (size_t)(row0 + r) * DI + k0 + skp,
                    As + w * 1024 + j * 512);
        }
        {
            int r = w * 16 + srow;
            gload16(Bw + (size_t)(col0 + r) * DI + k0 + skp,
                    Bs + w * 512);
        }
        __syncthreads();
        bf16x8 af[4], bfr[2];
#pragma unroll
        for (int mi = 0; mi < 4; mi++) {
            int row = wm * 64 + mi * 16 + (lane & 15);
            af[mi] = *(const bf16x8*)(As + row * 32 + ((lane >> 4) << 3));
        }
#pragma unroll
        for (int ni = 0; ni < 2; ni++) {
            int row = wn * 32 + ni * 16 + (lane & 15);
            bfr[ni] = *(const bf16x8*)(Bs + row * 32 + ((lane >> 4) << 3));
        }
#pragma unroll
        for (int mi = 0; mi < 4; mi++)
#pragma unroll
            for (int ni = 0; ni < 2; ni++)
                acc[mi][ni] = MFMA16(af[mi], bfr[ni], acc[mi][ni], 0, 0, 0);
        __syncthreads();
    }

#pragma unroll
    for (int mi = 0; mi < 4; mi++)
#pragma unroll
        for (int ni = 0; ni < 2; ni++) {
            int mbase = row0 + wm * 64 + mi * 16 + ((lane >> 4) << 2);
            int n = col0 + wn * 32 + ni * 16 + (lane & 15);
#pragma unroll
            for (int rr = 0; rr < 4; rr++) {
                size_t off = (size_t)(mbase + rr) * DM + n;
                Cf[off] += acc[mi][ni][rr];
            }
        }
}

// ---------------- causal conv1d (K=4) + bias + SiLU, x4 vectorized ----------
// thread -> (t, 4-channel group); exact grid TOK*DCONV/4/256 = 8704 blocks
__global__ __launch_bounds__(256) void conv_k(const u16* __restrict__ zx,
                                              const float* __restrict__ cw,
                                              const float* __restrict__ cb,
                                              u16* __restrict__ xbc) {
    int idx = blockIdx.x * 256 + threadIdx.x;
    int c0 = (idx % (DCONV / 4)) * 4;
    int t  = idx / (DCONV / 4);
    int s = t % SEQ;
    float a0 = cb[c0 + 0], a1 = cb[c0 + 1], a2 = cb[c0 + 2], a3 = cb[c0 + 3];
    float4 w0 = *(const float4*)(cw + (c0 + 0) * KC);
    float4 w1 = *(const float4*)(cw + (c0 + 1) * KC);
    float4 w2 = *(const float4*)(cw + (c0 + 2) * KC);
    float4 w3 = *(const float4*)(cw + (c0 + 3) * KC);
#pragma unroll
    for (int k = 0; k < KC; k++) {
        int ss = s - 3 + k;
        if (ss >= 0) {
            ushort4 v = *(const ushort4*)(zx + (size_t)(t - 3 + k) * DINP + DI + c0);
            float tap0 = (k == 0) ? w0.x : (k == 1) ? w0.y : (k == 2) ? w0.z : w0.w;
            float tap1 = (k == 0) ? w1.x : (k == 1) ? w1.y : (k == 2) ? w1.z : w1.w;
            float tap2 = (k == 0) ? w2.x : (k == 1) ? w2.y : (k == 2) ? w2.z : w2.w;
            float tap3 = (k == 0) ? w3.x : (k == 1) ? w3.y : (k == 2) ? w3.z : w3.w;
            a0 += tap0 * b2f(v.x);
            a1 += tap1 * b2f(v.y);
            a2 += tap2 * b2f(v.z);
            a3 += tap3 * b2f(v.w);
        }
    }
    a0 = a0 / (1.f + __expf(-a0));
    a1 = a1 / (1.f + __expf(-a1));
    a2 = a2 / (1.f + __expf(-a2));
    a3 = a3 / (1.f + __expf(-a3));
    ushort4 o;
    o.x = f2b(a0); o.y = f2b(a1); o.z = f2b(a2); o.w = f2b(a3);
    *(ushort4*)(xbc + (size_t)t * DCONV + c0) = o;
}

// ---------------- dt/acum: LDS-staged parallel load + fast cumsum -----------
// block = b*NC + c ; 256 threads
__global__ __launch_bounds__(256) void dtacum_k(const u16* __restrict__ zx,
                                                const float* __restrict__ dtb,
                                                const float* __restrict__ alog,
                                                float* __restrict__ dt,
                                                float* __restrict__ acum) {
    __shared__ float raw[64][33], dts[64][33], acs[64][33];
    int bc = blockIdx.x;
    int t0 = bc * CHK;
    int tid = threadIdx.x;
#pragma unroll
    for (int it = 0; it < 8; ++it) {
        int idx = it * 256 + tid;
        int l = idx >> 5, h = idx & 31;
        raw[l][h] = b2f(zx[(size_t)(t0 + l) * DINP + DI + DCONV + h]);
    }
    __syncthreads();
    if (tid < NH) {
        int h = tid;
        float bias = dtb[h];
        float Ah = -__expf(alog[h]);
        float run = 0.f;
#pragma unroll 4
        for (int l = 0; l < CHK; l++) {
            float x = raw[l][h] + bias;
            float d = (x > 20.f) ? x : log1pf(__expf(x));
            dts[l][h] = d;
            run += d * Ah;
            acs[l][h] = run;
        }
    }
    __syncthreads();
#pragma unroll
    for (int it = 0; it < 8; ++it) {
        int idx = it * 256 + tid;
        int l = idx >> 5, h = idx & 31;
        dt[(size_t)(t0 + l) * NH + h] = dts[l][h];
        acum[(size_t)(t0 + l) * NH + h] = acs[l][h];
    }
}

// ---------------- intra-chunk via MFMA (exp-factorized), bf16 yb/st ---------
// block = (b*NC+c)*(NH/HPB) + hg ; heads h = hg*HPB + 0..HPB-1
__global__ __launch_bounds__(256) void ydiagm_k(const u16* __restrict__ xbc,
                                                const float* __restrict__ dt_,
                                                const float* __restrict__ acum,
                                                const float* __restrict__ Dw,
                                                u16* __restrict__ yb,
                                                u16* __restrict__ st) {
    __shared__ u16 Bl[8192/2], Cl[8192/2], BlT[8192/2], CBm[8192/2], XpT[8192/2];
    __shared__ float cs[2][64], rs[2][64];
    const int tid = threadIdx.x;
    const int lane = tid & 63;
    const int w = tid >> 6;
    const int blk = blockIdx.x;
    const int hg = blk & (NH / HPB - 1);
    const int bc = blk / (NH / HPB);
    const int t0 = bc * CHK;

    for (int it = 0; it < 8; ++it) {
        int idx2 = it * 256 + tid;
        int r = idx2 >> 5;
        int j0 = (idx2 & 31) * 2;
        size_t rowp = (size_t)(t0 + r) * DCONV;
        uint32_t bv = *(const uint32_t*)(xbc + rowp + DI + j0);
        uint32_t cv = *(const uint32_t*)(xbc + rowp + DI + DSTT + j0);
        st32(Bl, r, j0, bv);
        st32(Cl, r, j0, cv);
        st16(BlT, j0, r, (u16)(bv & 0xffff));
        st16(BlT, j0 + 1, r, (u16)(bv >> 16));
    }
    {
        int4 z4 = {0, 0, 0, 0};
        *(int4*)((char*)CBm + tid * 16) = z4;
        *(int4*)((char*)CBm + 4096 + tid * 16) = z4;
    }
    if (tid < 64) {
        int h0 = hg * HPB;
        float a = acum[(size_t)(t0 + tid) * NH + h0];
        float d = dt_[(size_t)(t0 + tid) * NH + h0];
        cs[0][tid] = __expf(-a) * d;
        rs[0][tid] = __expf(a);
    }
    __syncthreads();

    {
        bf16x8 a0 = ldfrag(Cl, w * 16, 0, lane);
        bf16x8 a1 = ldfrag(Cl, w * 16, 1, lane);
        for (int stt = 0; stt <= w; ++stt) {
            f32x4 acc = {0.f, 0.f, 0.f, 0.f};
            acc = MFMA16(a0, ldfrag(Bl, stt * 16, 0, lane), acc, 0, 0, 0);
            acc = MFMA16(a1, ldfrag(Bl, stt * 16, 1, lane), acc, 0, 0, 0);
            int lrow = w * 16 + ((lane >> 4) << 2);
            int scol = stt * 16 + (lane & 15);
#pragma unroll
            for (int rr = 0; rr < 4; rr++) {
                int lg = lrow + rr;
                u16 v = (scol <= lg) ? f2b(acc[rr]) : (u16)0;
                st16(CBm, lg, scol, v);
            }
        }
    }

    int cur = 0;
    for (int hh = 0; hh < HPB; ++hh) {
        const int h = hg * HPB + hh;
        const int nxt = cur ^ 1;
        for (int it = 0; it < 8; ++it) {
            int s0 = it * 8 + w * 2;
            float c0 = cs[cur][s0], c1 = cs[cur][s0 + 1];
            float x0 = b2f(xbc[(size_t)(t0 + s0) * DCONV + h * HP + lane]);
            float x1 = b2f(xbc[(size_t)(t0 + s0 + 1) * DCONV + h * HP + lane]);
            uint32_t pk = (uint32_t)f2b(c0 * x0) | ((uint32_t)f2b(c1 * x1) << 16);
            st32(XpT, lane, s0, pk);
        }
        if (hh < HPB - 1 && tid < 64) {
            float a = acum[(size_t)(t0 + tid) * NH + h + 1];
            float d = dt_[(size_t)(t0 + tid) * NH + h + 1];
            cs[nxt][tid] = __expf(-a) * d;
            rs[nxt][tid] = __expf(a);
        }
        __syncthreads();

        {
            float Dh = Dw[h];
#pragma unroll
            for (int nt = 0; nt < 4; ++nt) {
                f32x4 acc = {0.f, 0.f, 0.f, 0.f};
                acc = MFMA16(ldfrag(CBm, w * 16, 0, lane),
                             ldfrag(XpT, nt * 16, 0, lane), acc, 0, 0, 0);
                if (w >= 2)
                    acc = MFMA16(ldfrag(CBm, w * 16, 1, lane),
                                 ldfrag(XpT, nt * 16, 1, lane), acc, 0, 0, 0);
                int lrow = w * 16 + ((lane >> 4) << 2);
                int pg = nt * 16 + (lane & 15);
#pragma unroll
                for (int rr = 0; rr < 4; rr++) {
                    int lg = lrow + rr;
                    float xr = b2f(xbc[(size_t)(t0 + lg) * DCONV + h * HP + pg]);
                    yb[(size_t)(t0 + lg) * DI + h * HP + pg] =
                        f2b(rs[cur][lg] * acc[rr] + Dh * xr);
                }
            }
        }
        {
            float dcv = rs[cur][63];
            u16* so = st + (size_t)(bc * NH + h) * (HP * DSTT);
            bf16x8 a0 = ldfrag(XpT, w * 16, 0, lane);
            bf16x8 a1 = ldfrag(XpT, w * 16, 1, lane);
#pragma unroll
            for (int nt = 0; nt < 4; ++nt) {
                f32x4 acc = {0.f, 0.f, 0.f, 0.f};
                acc = MFMA16(a0, ldfrag(BlT, nt * 16, 0, lane), acc, 0, 0, 0);
                acc = MFMA16(a1, ldfrag(BlT, nt * 16, 1, lane), acc, 0, 0, 0);
                int prow = w * 16 + ((lane >> 4) << 2);
                int ng = nt * 16 + (lane & 15);
#pragma unroll
                for (int rr = 0; rr < 4; rr++)
                    so[(size_t)(prow + rr) * DSTT + ng] = f2b(dcv * acc[rr]);
            }
        }
        __syncthreads();
        cur ^= 1;
    }
}

// ---------------- element-parallel inter-chunk scan (in place, bf16) --------
__global__ __launch_bounds__(256) void chainscan_k(const float* __restrict__ acum,
                                                   u16* __restrict__ st) {
    __shared__ float dc[NC];
    int blk = blockIdx.x;
    int slice = blk & 15;
    int bh = blk >> 4;
    int h = bh % NH, b = bh / NH;
    int tid = threadIdx.x;
    if (tid < NC)
        dc[tid] = __expf(acum[(size_t)(b * SEQ + tid * CHK + CHK - 1) * NH + h]);
    __syncthreads();
    int e = slice * 256 + tid;
    u16* p = st + ((size_t)(b * NC) * NH + h) * (HP * DSTT) + e;
    const size_t cstride = (size_t)NH * HP * DSTT;
    float s = 0.f;
#pragma unroll 4
    for (int c = 0; c < NC; c++) {
        float v = b2f(p[c * cstride]);
        p[c * cstride] = f2b(s);
        s = dc[c] * s + v;
    }
}

// ---------------- y_off via MFMA: yb[l,p] += ea[l]*sum_n C[l,n]*S[p,n] ------
// block = (b*NC + c)*NH + h ; bf16 yb RMW, bf16 S (direct copy to LDS)
__global__ __launch_bounds__(256) void yoffm_k(const u16* __restrict__ xbc,
                                               const float* __restrict__ acum,
                                               const u16* __restrict__ S,
                                               u16* __restrict__ yb) {
    __shared__ u16 Cl[4096], Sl[4096];   // two 64x64 bf16 tiles
    __shared__ float eal[64];
    const int blk = blockIdx.x;
    const int h = blk % NH;
    const int bc = blk / NH;
    const int t0 = bc * CHK;
    const int tid = threadIdx.x;
    const int lane = tid & 63;
    const int w = tid >> 6;

    for (int it = 0; it < 8; ++it) {
        int idx2 = it * 256 + tid;
        int r = idx2 >> 5;              // 0..63
        int j0 = (idx2 & 31) * 2;       // 0..62 even
        uint32_t cv = *(const uint32_t*)(xbc + (size_t)(t0 + r) * DCONV + DI + DSTT + j0);
        st32(Cl, r, j0, cv);
    }
    const u16* Sp = S + (size_t)blk * (HP * DSTT);
    for (int it = 0; it < 8; ++it) {
        int idx2 = it * 256 + tid;
        int p = idx2 >> 5;
        int j0 = (idx2 & 31) * 2;
        uint32_t sv = *(const uint32_t*)(Sp + p * DSTT + j0);
        st32(Sl, p, j0, sv);
    }
    if (tid < 64) eal[tid] = __expf(acum[(size_t)(t0 + tid) * NH + h]);
    __syncthreads();

    bf16x8 a0 = ldfrag(Cl, w * 16, 0, lane);
    bf16x8 a1 = ldfrag(Cl, w * 16, 1, lane);
#pragma unroll
    for (int nt = 0; nt < 4; ++nt) {
        f32x4 acc = {0.f, 0.f, 0.f, 0.f};
        acc = MFMA16(a0, ldfrag(Sl, nt * 16, 0, lane), acc, 0, 0, 0);
        acc = MFMA16(a1, ldfrag(Sl, nt * 16, 1, lane), acc, 0, 0, 0);
        int lrow = w * 16 + ((lane >> 4) << 2);
        int pg = nt * 16 + (lane & 15);
#pragma unroll
        for (int rr = 0; rr < 4; rr++) {
            int lg = lrow + rr;
            u16* yp = yb + (size_t)(t0 + lg) * DI + h * HP + pg;
            *yp = f2b(b2f(*yp) + eal[lg] * acc[rr]);
        }
    }
}

// ---------------- gate (y * silu(z)) + RMSNorm * rms_w -> bf16 --------------
__global__ __launch_bounds__(256) void gaterms_k(const u16* __restrict__ yb,
                                                 const u16* __restrict__ zx,
                                                 const float* __restrict__ rw,
                                                 u16* __restrict__ y2) {
    __shared__ float red[4];
    int t = blockIdx.x, tid = threadIdx.x;
    const u16* yr = yb + (size_t)t * DI;
    const u16* zr = zx + (size_t)t * DINP;
    int i0 = tid * 8;
    int4 yv4 = *(const int4*)(yr + i0);
    int4 zv4 = *(const int4*)(zr + i0);
    const u16* yp = (const u16*)&yv4;
    const u16* zp = (const u16*)&zv4;
    float g[8];
    float ss = 0.f;
#pragma unroll
    for (int j = 0; j < 8; j++) {
        float y = b2f(yp[j]);
        float z = b2f(zp[j]);
        float sl = z / (1.f + __expf(-z));
        float v = y * sl;
        g[j] = v;
        ss += v * v;
    }
#pragma unroll
    for (int off = 32; off; off >>= 1) ss += __shfl_down(ss, off);
    if ((tid & 63) == 0) red[tid >> 6] = ss;
    __syncthreads();
    float tot = red[0] + red[1] + red[2] + red[3];
    float sc = rsqrtf(tot * (1.f / DI) + 1e-5f);
    u16* yo = y2 + (size_t)t * DI + i0;
#pragma unroll
    for (int j = 0; j < 8; j++) yo[j] = f2b(g[j] * sc * rw[i0 + j]);
}

// ============================ host-side launch ==============================
extern "C" void kernel_launch(void* const* d_in, const int* in_sizes, int n_in,
                              void* d_out, int out_size, void* d_ws, size_t ws_size,
                              hipStream_t stream) {
    const int*   ids      = (const int*)d_in[0];
    const float* emb      = (const float*)d_in[2];
    const float* ln_w     = (const float*)d_in[3];
    const float* ln_b     = (const float*)d_in[4];
    const float* in_w     = (const float*)d_in[5];
    const float* conv_w   = (const float*)d_in[6];
    const float* conv_b   = (const float*)d_in[7];
    const float* dt_bias  = (const float*)d_in[8];
    const float* A_log    = (const float*)d_in[9];
    const float* Dw       = (const float*)d_in[10];
    const float* rms_w    = (const float*)d_in[11];
    const float* out_w    = (const float*)d_in[12];
    const float* norm_w   = (const float*)d_in[13];
    const float* norm_b   = (const float*)d_in[14];

    char* ws = (char*)d_ws;
    float* res    = (float*)(ws);                  // 16,777,216 B
    u16*   zx     = (u16*)  (ws + 16777216);       // 35,651,584 B (stride DINP)
    u16*   xbc    = (u16*)  (ws + 52428800);       // 17,825,792 B
    float* dt     = (float*)(ws + 70254592);       //    524,288 B
    float* acum   = (float*)(ws + 70778880);       //    524,288 B
    u16*   yb     = (u16*)  (ws + 71303168);       // 16,777,216 B (bf16)
    u16*   h      = (u16*)  (ws + 88080384);       //  8,388,608 B
    u16*   st     = (u16*)  (ws + 104857600);      // 16,777,216 B (bf16 now)
    u16*   y2     = (u16*)  (ws + 138412032);      // 16,777,216 B
    u16*   wpadAll= (u16*)  (ws + 155189248);      // 35,651,584 B (4 layers)
    u16*   obfAll = (u16*)  (ws + 190840832);      // 16,777,216 B (4 layers)
    const size_t NEED = 207618048;
    if (ws_size < NEED) return;

    // one-shot weight conversions (all layers)
    padw4_k<<<NLAY * DINP * DM / 4 / 256, 256, 0, stream>>>(in_w, wpadAll);
    cvt4_k<<<NLAY * DM * DI / 4 / 256, 256, 0, stream>>>(out_w, obfAll);

    embed_k<<<TOK, 256, 0, stream>>>(ids, emb, res);

    for (int l = 0; l < NLAY; ++l) {
        ln_k<u16><<<TOK, 256, 0, stream>>>(res, ln_w + l * DM, ln_b + l * DM, h);
        gemm_k<0, 1><<<(TOK / 128) * (DINP / 128), 256, 0, stream>>>(
            h, wpadAll + (size_t)l * DINP * DM, zx, nullptr, DINP, DM, DINP);
        conv_k<<<TOK * DCONV / 4 / 256, 256, 0, stream>>>(
            zx, conv_w + (size_t)l * DCONV * KC, conv_b + (size_t)l * DCONV, xbc);
        dtacum_k<<<BATCH * NC, 256, 0, stream>>>(
            zx, dt_bias + l * NH, A_log + l * NH, dt, acum);
        ydiagm_k<<<BATCH * NC * (NH / HPB), 256, 0, stream>>>(
            xbc, dt, acum, Dw + l * NH, yb, st);
        chainscan_k<<<BATCH * NH * 16, 256, 0, stream>>>(acum, st);
        yoffm_k<<<BATCH * NC * NH, 256, 0, stream>>>(xbc, acum, st, yb);
        gaterms_k<<<TOK, 256, 0, stream>>>(yb, zx, rms_w + (size_t)l * DI, y2);
        gemmo_k<<<512, 256, 0, stream>>>(
            y2, obfAll + (size_t)l * DM * DI, res);
    }

    ln_k<float><<<TOK, 256, 0, stream>>>(res, norm_w, norm_b, (float*)d_out);
}

// Round 22
// 846.844 us; speedup vs baseline: 1.1247x; 1.0150x over previous
//
#include <hip/hip_runtime.h>
#include <stdint.h>

typedef unsigned short u16;
using bf16x8 = __attribute__((ext_vector_type(8))) short;
using f32x4  = __attribute__((ext_vector_type(4))) float;

#define BATCH 2
#define SEQ   2048
#define TOK   (BATCH*SEQ)      // 4096 tokens
#define DM    1024
#define NLAY  4
#define DI    2048
#define DSTT  64               // state dim DS
#define NH    32               // heads
#define HP    64               // head dim P
#define KC    4                // conv kernel
#define CHK   64               // chunk len
#define NC    (SEQ/CHK)        // 32 chunks
#define DCONV (DI + 2*DSTT)    // 2176
#define DINR  (2*DI + 2*DSTT + NH) // 4256
#define DINP  4352             // padded to 128 multiple
#define HPB   4                // heads per ydiagm block

#define MFMA16 __builtin_amdgcn_mfma_f32_16x16x32_bf16

__device__ __forceinline__ float b2f(u16 u) {
    union { uint32_t i; float f; } v; v.i = ((uint32_t)u) << 16; return v.f;
}
__device__ __forceinline__ u16 f2b(float f) {
    union { float f; uint32_t i; } v; v.f = f;
    uint32_t x = v.i;
    uint32_t r = x + 0x7fffu + ((x >> 16) & 1u);
    return (u16)(r >> 16);
}
__device__ __forceinline__ void gload16(const u16* g, u16* l) {
    __builtin_amdgcn_global_load_lds(
        (const __attribute__((address_space(1))) void*)g,
        (__attribute__((address_space(3))) void*)l, 16, 0, 0);
}
// ---- 64x64 bf16 operand tiles: [2 k-tiles][64 rows][32 cols], gemm swizzle --
__device__ __forceinline__ int swzb(int byo) {
    return byo ^ (((byo >> 6) & 7) << 4);
}
__device__ __forceinline__ void st16(u16* base, int r, int k, u16 v) {
    int byo = ((k >> 5) << 12) | ((r * 32 + (k & 31)) << 1);
    *(u16*)((char*)base + swzb(byo)) = v;
}
__device__ __forceinline__ void st32(u16* base, int r, int k, uint32_t v) {
    int byo = ((k >> 5) << 12) | ((r * 32 + (k & 31)) << 1);   // k even
    *(uint32_t*)((char*)base + swzb(byo)) = v;
}
__device__ __forceinline__ bf16x8 ldfrag(const u16* base, int rbase, int kt, int lane) {
    int byo = (kt << 12) | (((rbase + (lane & 15)) * 32 + ((lane >> 4) << 3)) << 1);
    return *(const bf16x8*)((const char*)base + swzb(byo));
}

// ---------------- embedding gather: res[t,:] = emb[ids[t],:] (bf16) ---------
__global__ __launch_bounds__(256) void embed_k(const int* __restrict__ ids,
                                               const float* __restrict__ emb,
                                               u16* __restrict__ res) {
    int t = blockIdx.x, tid = threadIdx.x;
    int id = ids[t];
    const float* er = emb + (size_t)id * DM;
    int i0 = tid * 4;
    float4 v = *(const float4*)(er + i0);
    ushort4 o;
    o.x = f2b(v.x); o.y = f2b(v.y); o.z = f2b(v.z); o.w = f2b(v.w);
    *(ushort4*)(res + (size_t)t * DM + i0) = o;
}

// ---------------- layernorm over DM: src bf16 -> dst (bf16 or f32) ----------
template <typename OutT>
__global__ __launch_bounds__(256) void ln_k(const u16* __restrict__ src,
                                            const float* __restrict__ w,
                                            const float* __restrict__ bb,
                                            OutT* __restrict__ dst) {
    __shared__ float r1[4], r2[4];
    int t = blockIdx.x, tid = threadIdx.x;
    const u16* x = src + (size_t)t * DM;
    int i0 = tid * 4;
    ushort4 xv = *(const ushort4*)(x + i0);
    float v0 = b2f(xv.x), v1 = b2f(xv.y), v2 = b2f(xv.z), v3 = b2f(xv.w);
    float s1 = v0 + v1 + v2 + v3;
    float s2 = v0 * v0 + v1 * v1 + v2 * v2 + v3 * v3;
#pragma unroll
    for (int off = 32; off; off >>= 1) {
        s1 += __shfl_down(s1, off);
        s2 += __shfl_down(s2, off);
    }
    if ((tid & 63) == 0) { r1[tid >> 6] = s1; r2[tid >> 6] = s2; }
    __syncthreads();
    float S1 = r1[0] + r1[1] + r1[2] + r1[3];
    float S2 = r2[0] + r2[1] + r2[2] + r2[3];
    float mean = S1 * (1.f / DM);
    float var = S2 * (1.f / DM) - mean * mean;
    float inv = rsqrtf(var + 1e-5f);
    float4 wv = *(const float4*)(w + i0);
    float4 bv = *(const float4*)(bb + i0);
    OutT* d = dst + (size_t)t * DM + i0;
    float o0 = (v0 - mean) * inv * wv.x + bv.x;
    float o1 = (v1 - mean) * inv * wv.y + bv.y;
    float o2 = (v2 - mean) * inv * wv.z + bv.z;
    float o3 = (v3 - mean) * inv * wv.w + bv.w;
    if constexpr (sizeof(OutT) == 2) {
        d[0] = f2b(o0); d[1] = f2b(o1); d[2] = f2b(o2); d[3] = f2b(o3);
    } else {
        float4 o; o.x = o0; o.y = o1; o.z = o2; o.w = o3;
        *(float4*)d = o;
    }
}

// ------- pad+convert ALL layers in_w (f32) -> wpadAll (bf16, 4x4352x1024) ---
__global__ __launch_bounds__(256) void padw4_k(const float* __restrict__ w,
                                               u16* __restrict__ wp) {
    int idx = (blockIdx.x * 256 + threadIdx.x) * 4;
    int l = idx / (DINP * DM);
    int rem = idx - l * (DINP * DM);
    u16* dst = wp + (size_t)l * DINP * DM + rem;
    if (rem < DINR * DM) {
        float4 v = *(const float4*)(w + (size_t)l * DINR * DM + rem);
        dst[0] = f2b(v.x); dst[1] = f2b(v.y);
        dst[2] = f2b(v.z); dst[3] = f2b(v.w);
    } else {
        dst[0] = 0; dst[1] = 0; dst[2] = 0; dst[3] = 0;
    }
}

// ------- convert ALL layers out_w (f32) -> obfAll (bf16, 4x1024x2048) -------
__global__ __launch_bounds__(256) void cvt4_k(const float* __restrict__ src,
                                              u16* __restrict__ dst) {
    int idx = (blockIdx.x * 256 + threadIdx.x) * 4;
    float4 v = *(const float4*)(src + idx);
    dst[idx + 0] = f2b(v.x); dst[idx + 1] = f2b(v.y);
    dst[idx + 2] = f2b(v.z); dst[idx + 3] = f2b(v.w);
}

// ---------------- bf16 GEMM (m97 structure): C[m,n] = sum_k A[m,k]*B[n,k] ---
// Used only as gemm_k<0,1> (in-proj, bf16 LDS-coalesced store) — proven form.
template <int EPI, int KSPLIT>
__global__ __launch_bounds__(256) void gemm_k(const u16* __restrict__ A,
                                              const u16* __restrict__ Bw,
                                              u16* __restrict__ Cb,
                                              float* __restrict__ Cf,
                                              int N, int Kd, int ldc) {
    __shared__ u16 sm[8192];          // As = sm[0:4096], Bs = sm[4096:8192]
    u16* As = sm;
    u16* Bs = sm + 4096;
    const int tid = threadIdx.x;
    const int lane = tid & 63;
    const int w = tid >> 6;
    const int wm = w >> 1, wn = w & 1;
    const int nb = N >> 7;

    const int rowsPer = (gridDim.x / nb) >> 3;
    const int xcd = blockIdx.x & 7;
    const int local = blockIdx.x >> 3;
    const int bx = local / rowsPer;
    const int by = xcd * rowsPer + (local % rowsPer);
    const int row0 = by << 7, col0 = bx << 7;

    const int Kslice = Kd / KSPLIT;
    const int kbase = blockIdx.y * Kslice;

    const int srow = lane >> 2;
    const int skp  = (lane & 3) << 3;

    f32x4 zero = {0.f, 0.f, 0.f, 0.f};
    f32x4 acc[4][4];
#pragma unroll
    for (int i = 0; i < 4; i++)
#pragma unroll
        for (int j = 0; j < 4; j++) acc[i][j] = zero;

    const int tiles = Kslice >> 5;
    for (int kt = 0; kt < tiles; ++kt) {
        const int k0 = kbase + (kt << 5);
#pragma unroll
        for (int j = 0; j < 2; ++j) {
            int r = w * 32 + j * 16 + srow;
            gload16(A + (size_t)(row0 + r) * Kd + k0 + skp,
                    As + w * 1024 + j * 512);
            gload16(Bw + (size_t)(col0 + r) * Kd + k0 + skp,
                    Bs + w * 1024 + j * 512);
        }
        __syncthreads();
        bf16x8 af[4], bfr[4];
#pragma unroll
        for (int mi = 0; mi < 4; mi++) {
            int row = wm * 64 + mi * 16 + (lane & 15);
            af[mi] = *(const bf16x8*)(As + row * 32 + ((lane >> 4) << 3));
        }
#pragma unroll
        for (int ni = 0; ni < 4; ni++) {
            int row = wn * 64 + ni * 16 + (lane & 15);
            bfr[ni] = *(const bf16x8*)(Bs + row * 32 + ((lane >> 4) << 3));
        }
#pragma unroll
        for (int mi = 0; mi < 4; mi++)
#pragma unroll
            for (int ni = 0; ni < 4; ni++)
                acc[mi][ni] = MFMA16(af[mi], bfr[ni], acc[mi][ni], 0, 0, 0);
        __syncthreads();
    }

    if (EPI == 0) {
#pragma unroll
        for (int half = 0; half < 2; ++half) {
            if (wm == half) {
#pragma unroll
                for (int mi = 0; mi < 4; mi++)
#pragma unroll
                    for (int ni = 0; ni < 4; ni++) {
                        int lr = mi * 16 + ((lane >> 4) << 2);
                        int col = wn * 64 + ni * 16 + (lane & 15);
#pragma unroll
                        for (int rr = 0; rr < 4; rr++)
                            sm[(lr + rr) * 128 + col] = f2b(acc[mi][ni][rr]);
                    }
            }
            __syncthreads();
#pragma unroll
            for (int q = 0; q < 4; q++) {
                int lr = w * 16 + q * 4 + (lane >> 4);
                int colb = (lane & 15) * 16;
                int4 v = *(const int4*)((const char*)sm + lr * 256 + colb);
                char* gp = (char*)(Cb + (size_t)(row0 + half * 64 + lr) * ldc + col0) + colb;
                *(int4*)gp = v;
            }
            __syncthreads();
        }
    } else {
#pragma unroll
        for (int mi = 0; mi < 4; mi++)
#pragma unroll
            for (int ni = 0; ni < 4; ni++) {
                int mbase = row0 + wm * 64 + mi * 16 + ((lane >> 4) << 2);
                int n = col0 + wn * 64 + ni * 16 + (lane & 15);
#pragma unroll
                for (int rr = 0; rr < 4; rr++) {
                    size_t off = (size_t)(mbase + rr) * ldc + n;
                    if (KSPLIT == 1) Cf[off] += acc[mi][ni][rr];
                    else atomicAdd(Cf + off, acc[mi][ni][rr]);
                }
            }
    }
}

// ---------------- out-proj GEMM: res[m,n] += sum_k y2[m,k]*obf[n,k] ---------
// 128x64 tile, 512 blocks, deterministic bf16 RMW (no atomics).
__global__ __launch_bounds__(256) void gemmo_k(const u16* __restrict__ A,
                                               const u16* __restrict__ Bw,
                                               u16* __restrict__ Cf) {
    __shared__ u16 As[128 * 32];      // 8 KB
    __shared__ u16 Bs[64 * 32];       // 4 KB
    const int tid = threadIdx.x;
    const int lane = tid & 63;
    const int w = tid >> 6;
    const int wm = w >> 1, wn = w & 1;

    const int rowsPer = 4;
    const int xcd = blockIdx.x & 7;
    const int local = blockIdx.x >> 3;
    const int bx = local / rowsPer;
    const int by = xcd * rowsPer + (local % rowsPer);
    const int row0 = by << 7, col0 = bx << 6;

    const int srow = lane >> 2;          // 0..15
    const int skp  = (lane & 3) << 3;    // 0,8,16,24

    f32x4 zero = {0.f, 0.f, 0.f, 0.f};
    f32x4 acc[4][2];
#pragma unroll
    for (int i = 0; i < 4; i++)
#pragma unroll
        for (int j = 0; j < 2; j++) acc[i][j] = zero;

    const int tiles = DI >> 5;           // 64
    for (int kt = 0; kt < tiles; ++kt) {
        const int k0 = kt << 5;
#pragma unroll
        for (int j = 0; j < 2; ++j) {
            int r = w * 32 + j * 16 + srow;
            gload16(A + (size_t)(row0 + r) * DI + k0 + skp,
                    As + w * 1024 + j * 512);
        }
        {
            int r = w * 16 + srow;
            gload16(Bw + (size_t)(col0 + r) * DI + k0 + skp,
                    Bs + w * 512);
        }
        __syncthreads();
        bf16x8 af[4], bfr[2];
#pragma unroll
        for (int mi = 0; mi < 4; mi++) {
            int row = wm * 64 + mi * 16 + (lane & 15);
            af[mi] = *(const bf16x8*)(As + row * 32 + ((lane >> 4) << 3));
        }
#pragma unroll
        for (int ni = 0; ni < 2; ni++) {
            int row = wn * 32 + ni * 16 + (lane & 15);
            bfr[ni] = *(const bf16x8*)(Bs + row * 32 + ((lane >> 4) << 3));
        }
#pragma unroll
        for (int mi = 0; mi < 4; mi++)
#pragma unroll
            for (int ni = 0; ni < 2; ni++)
                acc[mi][ni] = MFMA16(af[mi], bfr[ni], acc[mi][ni], 0, 0, 0);
        __syncthreads();
    }

#pragma unroll
    for (int mi = 0; mi < 4; mi++)
#pragma unroll
        for (int ni = 0; ni < 2; ni++) {
            int mbase = row0 + wm * 64 + mi * 16 + ((lane >> 4) << 2);
            int n = col0 + wn * 32 + ni * 16 + (lane & 15);
#pragma unroll
            for (int rr = 0; rr < 4; rr++) {
                size_t off = (size_t)(mbase + rr) * DM + n;
                Cf[off] = f2b(b2f(Cf[off]) + acc[mi][ni][rr]);
            }
        }
}

// ---------------- causal conv1d (K=4) + bias + SiLU, x4 vectorized ----------
// thread -> (t, 4-channel group); exact grid TOK*DCONV/4/256 = 8704 blocks
__global__ __launch_bounds__(256) void conv_k(const u16* __restrict__ zx,
                                              const float* __restrict__ cw,
                                              const float* __restrict__ cb,
                                              u16* __restrict__ xbc) {
    int idx = blockIdx.x * 256 + threadIdx.x;
    int c0 = (idx % (DCONV / 4)) * 4;
    int t  = idx / (DCONV / 4);
    int s = t % SEQ;
    float a0 = cb[c0 + 0], a1 = cb[c0 + 1], a2 = cb[c0 + 2], a3 = cb[c0 + 3];
    float4 w0 = *(const float4*)(cw + (c0 + 0) * KC);
    float4 w1 = *(const float4*)(cw + (c0 + 1) * KC);
    float4 w2 = *(const float4*)(cw + (c0 + 2) * KC);
    float4 w3 = *(const float4*)(cw + (c0 + 3) * KC);
#pragma unroll
    for (int k = 0; k < KC; k++) {
        int ss = s - 3 + k;
        if (ss >= 0) {
            ushort4 v = *(const ushort4*)(zx + (size_t)(t - 3 + k) * DINP + DI + c0);
            float tap0 = (k == 0) ? w0.x : (k == 1) ? w0.y : (k == 2) ? w0.z : w0.w;
            float tap1 = (k == 0) ? w1.x : (k == 1) ? w1.y : (k == 2) ? w1.z : w1.w;
            float tap2 = (k == 0) ? w2.x : (k == 1) ? w2.y : (k == 2) ? w2.z : w2.w;
            float tap3 = (k == 0) ? w3.x : (k == 1) ? w3.y : (k == 2) ? w3.z : w3.w;
            a0 += tap0 * b2f(v.x);
            a1 += tap1 * b2f(v.y);
            a2 += tap2 * b2f(v.z);
            a3 += tap3 * b2f(v.w);
        }
    }
    a0 = a0 / (1.f + __expf(-a0));
    a1 = a1 / (1.f + __expf(-a1));
    a2 = a2 / (1.f + __expf(-a2));
    a3 = a3 / (1.f + __expf(-a3));
    ushort4 o;
    o.x = f2b(a0); o.y = f2b(a1); o.z = f2b(a2); o.w = f2b(a3);
    *(ushort4*)(xbc + (size_t)t * DCONV + c0) = o;
}

// ---------------- dt/acum: LDS-staged parallel load + fast cumsum -----------
// block = b*NC + c ; 256 threads
__global__ __launch_bounds__(256) void dtacum_k(const u16* __restrict__ zx,
                                                const float* __restrict__ dtb,
                                                const float* __restrict__ alog,
                                                float* __restrict__ dt,
                                                float* __restrict__ acum) {
    __shared__ float raw[64][33], dts[64][33], acs[64][33];
    int bc = blockIdx.x;
    int t0 = bc * CHK;
    int tid = threadIdx.x;
#pragma unroll
    for (int it = 0; it < 8; ++it) {
        int idx = it * 256 + tid;
        int l = idx >> 5, h = idx & 31;
        raw[l][h] = b2f(zx[(size_t)(t0 + l) * DINP + DI + DCONV + h]);
    }
    __syncthreads();
    if (tid < NH) {
        int h = tid;
        float bias = dtb[h];
        float Ah = -__expf(alog[h]);
        float run = 0.f;
#pragma unroll 4
        for (int l = 0; l < CHK; l++) {
            float x = raw[l][h] + bias;
            float d = (x > 20.f) ? x : log1pf(__expf(x));
            dts[l][h] = d;
            run += d * Ah;
            acs[l][h] = run;
        }
    }
    __syncthreads();
#pragma unroll
    for (int it = 0; it < 8; ++it) {
        int idx = it * 256 + tid;
        int l = idx >> 5, h = idx & 31;
        dt[(size_t)(t0 + l) * NH + h] = dts[l][h];
        acum[(size_t)(t0 + l) * NH + h] = acs[l][h];
    }
}

// ---------------- intra-chunk via MFMA (exp-factorized), bf16 yb/st ---------
// block = (b*NC+c)*(NH/HPB) + hg ; heads h = hg*HPB + 0..HPB-1
__global__ __launch_bounds__(256) void ydiagm_k(const u16* __restrict__ xbc,
                                                const float* __restrict__ dt_,
                                                const float* __restrict__ acum,
                                                const float* __restrict__ Dw,
                                                u16* __restrict__ yb,
                                                u16* __restrict__ st) {
    __shared__ u16 Bl[8192/2], Cl[8192/2], BlT[8192/2], CBm[8192/2], XpT[8192/2];
    __shared__ float cs[2][64], rs[2][64];
    const int tid = threadIdx.x;
    const int lane = tid & 63;
    const int w = tid >> 6;
    const int blk = blockIdx.x;
    const int hg = blk & (NH / HPB - 1);
    const int bc = blk / (NH / HPB);
    const int t0 = bc * CHK;

    for (int it = 0; it < 8; ++it) {
        int idx2 = it * 256 + tid;
        int r = idx2 >> 5;
        int j0 = (idx2 & 31) * 2;
        size_t rowp = (size_t)(t0 + r) * DCONV;
        uint32_t bv = *(const uint32_t*)(xbc + rowp + DI + j0);
        uint32_t cv = *(const uint32_t*)(xbc + rowp + DI + DSTT + j0);
        st32(Bl, r, j0, bv);
        st32(Cl, r, j0, cv);
        st16(BlT, j0, r, (u16)(bv & 0xffff));
        st16(BlT, j0 + 1, r, (u16)(bv >> 16));
    }
    {
        int4 z4 = {0, 0, 0, 0};
        *(int4*)((char*)CBm + tid * 16) = z4;
        *(int4*)((char*)CBm + 4096 + tid * 16) = z4;
    }
    if (tid < 64) {
        int h0 = hg * HPB;
        float a = acum[(size_t)(t0 + tid) * NH + h0];
        float d = dt_[(size_t)(t0 + tid) * NH + h0];
        cs[0][tid] = __expf(-a) * d;
        rs[0][tid] = __expf(a);
    }
    __syncthreads();

    {
        bf16x8 a0 = ldfrag(Cl, w * 16, 0, lane);
        bf16x8 a1 = ldfrag(Cl, w * 16, 1, lane);
        for (int stt = 0; stt <= w; ++stt) {
            f32x4 acc = {0.f, 0.f, 0.f, 0.f};
            acc = MFMA16(a0, ldfrag(Bl, stt * 16, 0, lane), acc, 0, 0, 0);
            acc = MFMA16(a1, ldfrag(Bl, stt * 16, 1, lane), acc, 0, 0, 0);
            int lrow = w * 16 + ((lane >> 4) << 2);
            int scol = stt * 16 + (lane & 15);
#pragma unroll
            for (int rr = 0; rr < 4; rr++) {
                int lg = lrow + rr;
                u16 v = (scol <= lg) ? f2b(acc[rr]) : (u16)0;
                st16(CBm, lg, scol, v);
            }
        }
    }

    int cur = 0;
    for (int hh = 0; hh < HPB; ++hh) {
        const int h = hg * HPB + hh;
        const int nxt = cur ^ 1;
        for (int it = 0; it < 8; ++it) {
            int s0 = it * 8 + w * 2;
            float c0 = cs[cur][s0], c1 = cs[cur][s0 + 1];
            float x0 = b2f(xbc[(size_t)(t0 + s0) * DCONV + h * HP + lane]);
            float x1 = b2f(xbc[(size_t)(t0 + s0 + 1) * DCONV + h * HP + lane]);
            uint32_t pk = (uint32_t)f2b(c0 * x0) | ((uint32_t)f2b(c1 * x1) << 16);
            st32(XpT, lane, s0, pk);
        }
        if (hh < HPB - 1 && tid < 64) {
            float a = acum[(size_t)(t0 + tid) * NH + h + 1];
            float d = dt_[(size_t)(t0 + tid) * NH + h + 1];
            cs[nxt][tid] = __expf(-a) * d;
            rs[nxt][tid] = __expf(a);
        }
        __syncthreads();

        {
            float Dh = Dw[h];
#pragma unroll
            for (int nt = 0; nt < 4; ++nt) {
                f32x4 acc = {0.f, 0.f, 0.f, 0.f};
                acc = MFMA16(ldfrag(CBm, w * 16, 0, lane),
                             ldfrag(XpT, nt * 16, 0, lane), acc, 0, 0, 0);
                if (w >= 2)
                    acc = MFMA16(ldfrag(CBm, w * 16, 1, lane),
                                 ldfrag(XpT, nt * 16, 1, lane), acc, 0, 0, 0);
                int lrow = w * 16 + ((lane >> 4) << 2);
                int pg = nt * 16 + (lane & 15);
#pragma unroll
                for (int rr = 0; rr < 4; rr++) {
                    int lg = lrow + rr;
                    float xr = b2f(xbc[(size_t)(t0 + lg) * DCONV + h * HP + pg]);
                    yb[(size_t)(t0 + lg) * DI + h * HP + pg] =
                        f2b(rs[cur][lg] * acc[rr] + Dh * xr);
                }
            }
        }
        {
            float dcv = rs[cur][63];
            u16* so = st + (size_t)(bc * NH + h) * (HP * DSTT);
            bf16x8 a0 = ldfrag(XpT, w * 16, 0, lane);
            bf16x8 a1 = ldfrag(XpT, w * 16, 1, lane);
#pragma unroll
            for (int nt = 0; nt < 4; ++nt) {
                f32x4 acc = {0.f, 0.f, 0.f, 0.f};
                acc = MFMA16(a0, ldfrag(BlT, nt * 16, 0, lane), acc, 0, 0, 0);
                acc = MFMA16(a1, ldfrag(BlT, nt * 16, 1, lane), acc, 0, 0, 0);
                int prow = w * 16 + ((lane >> 4) << 2);
                int ng = nt * 16 + (lane & 15);
#pragma unroll
                for (int rr = 0; rr < 4; rr++)
                    so[(size_t)(prow + rr) * DSTT + ng] = f2b(dcv * acc[rr]);
            }
        }
        __syncthreads();
        cur ^= 1;
    }
}

// ---------------- element-parallel inter-chunk scan (in place, bf16) --------
__global__ __launch_bounds__(256) void chainscan_k(const float* __restrict__ acum,
                                                   u16* __restrict__ st) {
    __shared__ float dc[NC];
    int blk = blockIdx.x;
    int slice = blk & 15;
    int bh = blk >> 4;
    int h = bh % NH, b = bh / NH;
    int tid = threadIdx.x;
    if (tid < NC)
        dc[tid] = __expf(acum[(size_t)(b * SEQ + tid * CHK + CHK - 1) * NH + h]);
    __syncthreads();
    int e = slice * 256 + tid;
    u16* p = st + ((size_t)(b * NC) * NH + h) * (HP * DSTT) + e;
    const size_t cstride = (size_t)NH * HP * DSTT;
    float s = 0.f;
#pragma unroll 4
    for (int c = 0; c < NC; c++) {
        float v = b2f(p[c * cstride]);
        p[c * cstride] = f2b(s);
        s = dc[c] * s + v;
    }
}

// ---------------- y_off via MFMA: yb[l,p] += ea[l]*sum_n C[l,n]*S[p,n] ------
// block = (b*NC + c)*NH + h ; bf16 yb RMW, bf16 S (direct copy to LDS)
__global__ __launch_bounds__(256) void yoffm_k(const u16* __restrict__ xbc,
                                               const float* __restrict__ acum,
                                               const u16* __restrict__ S,
                                               u16* __restrict__ yb) {
    __shared__ u16 Cl[4096], Sl[4096];   // two 64x64 bf16 tiles
    __shared__ float eal[64];
    const int blk = blockIdx.x;
    const int h = blk % NH;
    const int bc = blk / NH;
    const int t0 = bc * CHK;
    const int tid = threadIdx.x;
    const int lane = tid & 63;
    const int w = tid >> 6;

    for (int it = 0; it < 8; ++it) {
        int idx2 = it * 256 + tid;
        int r = idx2 >> 5;              // 0..63
        int j0 = (idx2 & 31) * 2;       // 0..62 even
        uint32_t cv = *(const uint32_t*)(xbc + (size_t)(t0 + r) * DCONV + DI + DSTT + j0);
        st32(Cl, r, j0, cv);
    }
    const u16* Sp = S + (size_t)blk * (HP * DSTT);
    for (int it = 0; it < 8; ++it) {
        int idx2 = it * 256 + tid;
        int p = idx2 >> 5;
        int j0 = (idx2 & 31) * 2;
        uint32_t sv = *(const uint32_t*)(Sp + p * DSTT + j0);
        st32(Sl, p, j0, sv);
    }
    if (tid < 64) eal[tid] = __expf(acum[(size_t)(t0 + tid) * NH + h]);
    __syncthreads();

    bf16x8 a0 = ldfrag(Cl, w * 16, 0, lane);
    bf16x8 a1 = ldfrag(Cl, w * 16, 1, lane);
#pragma unroll
    for (int nt = 0; nt < 4; ++nt) {
        f32x4 acc = {0.f, 0.f, 0.f, 0.f};
        acc = MFMA16(a0, ldfrag(Sl, nt * 16, 0, lane), acc, 0, 0, 0);
        acc = MFMA16(a1, ldfrag(Sl, nt * 16, 1, lane), acc, 0, 0, 0);
        int lrow = w * 16 + ((lane >> 4) << 2);
        int pg = nt * 16 + (lane & 15);
#pragma unroll
        for (int rr = 0; rr < 4; rr++) {
            int lg = lrow + rr;
            u16* yp = yb + (size_t)(t0 + lg) * DI + h * HP + pg;
            *yp = f2b(b2f(*yp) + eal[lg] * acc[rr]);
        }
    }
}

// ---------------- gate (y * silu(z)) + RMSNorm * rms_w -> bf16 --------------
__global__ __launch_bounds__(256) void gaterms_k(const u16* __restrict__ yb,
                                                 const u16* __restrict__ zx,
                                                 const float* __restrict__ rw,
                                                 u16* __restrict__ y2) {
    __shared__ float red[4];
    int t = blockIdx.x, tid = threadIdx.x;
    const u16* yr = yb + (size_t)t * DI;
    const u16* zr = zx + (size_t)t * DINP;
    int i0 = tid * 8;
    int4 yv4 = *(const int4*)(yr + i0);
    int4 zv4 = *(const int4*)(zr + i0);
    const u16* yp = (const u16*)&yv4;
    const u16* zp = (const u16*)&zv4;
    float g[8];
    float ss = 0.f;
#pragma unroll
    for (int j = 0; j < 8; j++) {
        float y = b2f(yp[j]);
        float z = b2f(zp[j]);
        float sl = z / (1.f + __expf(-z));
        float v = y * sl;
        g[j] = v;
        ss += v * v;
    }
#pragma unroll
    for (int off = 32; off; off >>= 1) ss += __shfl_down(ss, off);
    if ((tid & 63) == 0) red[tid >> 6] = ss;
    __syncthreads();
    float tot = red[0] + red[1] + red[2] + red[3];
    float sc = rsqrtf(tot * (1.f / DI) + 1e-5f);
    u16* yo = y2 + (size_t)t * DI + i0;
#pragma unroll
    for (int j = 0; j < 8; j++) yo[j] = f2b(g[j] * sc * rw[i0 + j]);
}

// ============================ host-side launch ==============================
extern "C" void kernel_launch(void* const* d_in, const int* in_sizes, int n_in,
                              void* d_out, int out_size, void* d_ws, size_t ws_size,
                              hipStream_t stream) {
    const int*   ids      = (const int*)d_in[0];
    const float* emb      = (const float*)d_in[2];
    const float* ln_w     = (const float*)d_in[3];
    const float* ln_b     = (const float*)d_in[4];
    const float* in_w     = (const float*)d_in[5];
    const float* conv_w   = (const float*)d_in[6];
    const float* conv_b   = (const float*)d_in[7];
    const float* dt_bias  = (const float*)d_in[8];
    const float* A_log    = (const float*)d_in[9];
    const float* Dw       = (const float*)d_in[10];
    const float* rms_w    = (const float*)d_in[11];
    const float* out_w    = (const float*)d_in[12];
    const float* norm_w   = (const float*)d_in[13];
    const float* norm_b   = (const float*)d_in[14];

    char* ws = (char*)d_ws;
    u16*   res    = (u16*)  (ws);                  //  8,388,608 B (bf16 now)
    u16*   zx     = (u16*)  (ws + 16777216);       // 35,651,584 B (stride DINP)
    u16*   xbc    = (u16*)  (ws + 52428800);       // 17,825,792 B
    float* dt     = (float*)(ws + 70254592);       //    524,288 B
    float* acum   = (float*)(ws + 70778880);       //    524,288 B
    u16*   yb     = (u16*)  (ws + 71303168);       // 16,777,216 B (bf16)
    u16*   h      = (u16*)  (ws + 88080384);       //  8,388,608 B
    u16*   st     = (u16*)  (ws + 104857600);      // 16,777,216 B (bf16)
    u16*   y2     = (u16*)  (ws + 138412032);      // 16,777,216 B
    u16*   wpadAll= (u16*)  (ws + 155189248);      // 35,651,584 B (4 layers)
    u16*   obfAll = (u16*)  (ws + 190840832);      // 16,777,216 B (4 layers)
    const size_t NEED = 207618048;
    if (ws_size < NEED) return;

    // one-shot weight conversions (all layers)
    padw4_k<<<NLAY * DINP * DM / 4 / 256, 256, 0, stream>>>(in_w, wpadAll);
    cvt4_k<<<NLAY * DM * DI / 4 / 256, 256, 0, stream>>>(out_w, obfAll);

    embed_k<<<TOK, 256, 0, stream>>>(ids, emb, res);

    for (int l = 0; l < NLAY; ++l) {
        ln_k<u16><<<TOK, 256, 0, stream>>>(res, ln_w + l * DM, ln_b + l * DM, h);
        gemm_k<0, 1><<<(TOK / 128) * (DINP / 128), 256, 0, stream>>>(
            h, wpadAll + (size_t)l * DINP * DM, zx, nullptr, DINP, DM, DINP);
        conv_k<<<TOK * DCONV / 4 / 256, 256, 0, stream>>>(
            zx, conv_w + (size_t)l * DCONV * KC, conv_b + (size_t)l * DCONV, xbc);
        dtacum_k<<<BATCH * NC, 256, 0, stream>>>(
            zx, dt_bias + l * NH, A_log + l * NH, dt, acum);
        ydiagm_k<<<BATCH * NC * (NH / HPB), 256, 0, stream>>>(
            xbc, dt, acum, Dw + l * NH, yb, st);
        chainscan_k<<<BATCH * NH * 16, 256, 0, stream>>>(acum, st);
        yoffm_k<<<BATCH * NC * NH, 256, 0, stream>>>(xbc, acum, st, yb);
        gaterms_k<<<TOK, 256, 0, stream>>>(yb, zx, rms_w + (size_t)l * DI, y2);
        gemmo_k<<<512, 256, 0, stream>>>(
            y2, obfAll + (size_t)l * DM * DI, res);
    }

    ln_k<float><<<TOK, 256, 0, stream>>>(res, norm_w, norm_b, (float*)d_out);
}

// Round 23
// 843.317 us; speedup vs baseline: 1.1294x; 1.0042x over previous
//
#include <hip/hip_runtime.h>
#include <stdint.h>

typedef unsigned short u16;
using bf16x8 = __attribute__((ext_vector_type(8))) short;
using f32x4  = __attribute__((ext_vector_type(4))) float;

#define BATCH 2
#define SEQ   2048
#define TOK   (BATCH*SEQ)      // 4096 tokens
#define DM    1024
#define NLAY  4
#define DI    2048
#define DSTT  64               // state dim DS
#define NH    32               // heads
#define HP    64               // head dim P
#define KC    4                // conv kernel
#define CHK   64               // chunk len
#define NC    (SEQ/CHK)        // 32 chunks
#define DCONV (DI + 2*DSTT)    // 2176
#define DINR  (2*DI + 2*DSTT + NH) // 4256
#define DINP  4352             // padded to 128 multiple
#define HPB   4                // heads per ydiagm block

#define MFMA16 __builtin_amdgcn_mfma_f32_16x16x32_bf16

__device__ __forceinline__ float b2f(u16 u) {
    union { uint32_t i; float f; } v; v.i = ((uint32_t)u) << 16; return v.f;
}
__device__ __forceinline__ u16 f2b(float f) {
    union { float f; uint32_t i; } v; v.f = f;
    uint32_t x = v.i;
    uint32_t r = x + 0x7fffu + ((x >> 16) & 1u);
    return (u16)(r >> 16);
}
__device__ __forceinline__ void gload16(const u16* g, u16* l) {
    __builtin_amdgcn_global_load_lds(
        (const __attribute__((address_space(1))) void*)g,
        (__attribute__((address_space(3))) void*)l, 16, 0, 0);
}
// ---- 64x64 bf16 operand tiles: [2 k-tiles][64 rows][32 cols], gemm swizzle --
__device__ __forceinline__ int swzb(int byo) {
    return byo ^ (((byo >> 6) & 7) << 4);
}
__device__ __forceinline__ void st16(u16* base, int r, int k, u16 v) {
    int byo = ((k >> 5) << 12) | ((r * 32 + (k & 31)) << 1);
    *(u16*)((char*)base + swzb(byo)) = v;
}
__device__ __forceinline__ void st32(u16* base, int r, int k, uint32_t v) {
    int byo = ((k >> 5) << 12) | ((r * 32 + (k & 31)) << 1);   // k even
    *(uint32_t*)((char*)base + swzb(byo)) = v;
}
__device__ __forceinline__ bf16x8 ldfrag(const u16* base, int rbase, int kt, int lane) {
    int byo = (kt << 12) | (((rbase + (lane & 15)) * 32 + ((lane >> 4) << 3)) << 1);
    return *(const bf16x8*)((const char*)base + swzb(byo));
}

// ---------------- embedding gather: res[t,:] = emb[ids[t],:] (bf16) ---------
__global__ __launch_bounds__(256) void embed_k(const int* __restrict__ ids,
                                               const float* __restrict__ emb,
                                               u16* __restrict__ res) {
    int t = blockIdx.x, tid = threadIdx.x;
    int id = ids[t];
    const float* er = emb + (size_t)id * DM;
    int i0 = tid * 4;
    float4 v = *(const float4*)(er + i0);
    ushort4 o;
    o.x = f2b(v.x); o.y = f2b(v.y); o.z = f2b(v.z); o.w = f2b(v.w);
    *(ushort4*)(res + (size_t)t * DM + i0) = o;
}

// ---------------- layernorm over DM: src bf16 -> dst (bf16 or f32) ----------
template <typename OutT>
__global__ __launch_bounds__(256) void ln_k(const u16* __restrict__ src,
                                            const float* __restrict__ w,
                                            const float* __restrict__ bb,
                                            OutT* __restrict__ dst) {
    __shared__ float r1[4], r2[4];
    int t = blockIdx.x, tid = threadIdx.x;
    const u16* x = src + (size_t)t * DM;
    int i0 = tid * 4;
    ushort4 xv = *(const ushort4*)(x + i0);
    float v0 = b2f(xv.x), v1 = b2f(xv.y), v2 = b2f(xv.z), v3 = b2f(xv.w);
    float s1 = v0 + v1 + v2 + v3;
    float s2 = v0 * v0 + v1 * v1 + v2 * v2 + v3 * v3;
#pragma unroll
    for (int off = 32; off; off >>= 1) {
        s1 += __shfl_down(s1, off);
        s2 += __shfl_down(s2, off);
    }
    if ((tid & 63) == 0) { r1[tid >> 6] = s1; r2[tid >> 6] = s2; }
    __syncthreads();
    float S1 = r1[0] + r1[1] + r1[2] + r1[3];
    float S2 = r2[0] + r2[1] + r2[2] + r2[3];
    float mean = S1 * (1.f / DM);
    float var = S2 * (1.f / DM) - mean * mean;
    float inv = rsqrtf(var + 1e-5f);
    float4 wv = *(const float4*)(w + i0);
    float4 bv = *(const float4*)(bb + i0);
    OutT* d = dst + (size_t)t * DM + i0;
    float o0 = (v0 - mean) * inv * wv.x + bv.x;
    float o1 = (v1 - mean) * inv * wv.y + bv.y;
    float o2 = (v2 - mean) * inv * wv.z + bv.z;
    float o3 = (v3 - mean) * inv * wv.w + bv.w;
    if constexpr (sizeof(OutT) == 2) {
        d[0] = f2b(o0); d[1] = f2b(o1); d[2] = f2b(o2); d[3] = f2b(o3);
    } else {
        float4 o; o.x = o0; o.y = o1; o.z = o2; o.w = o3;
        *(float4*)d = o;
    }
}

// ------- pad+convert ALL layers in_w (f32) -> wpadAll (bf16, 4x4352x1024) ---
__global__ __launch_bounds__(256) void padw4_k(const float* __restrict__ w,
                                               u16* __restrict__ wp) {
    int idx = (blockIdx.x * 256 + threadIdx.x) * 4;
    int l = idx / (DINP * DM);
    int rem = idx - l * (DINP * DM);
    u16* dst = wp + (size_t)l * DINP * DM + rem;
    if (rem < DINR * DM) {
        float4 v = *(const float4*)(w + (size_t)l * DINR * DM + rem);
        dst[0] = f2b(v.x); dst[1] = f2b(v.y);
        dst[2] = f2b(v.z); dst[3] = f2b(v.w);
    } else {
        dst[0] = 0; dst[1] = 0; dst[2] = 0; dst[3] = 0;
    }
}

// ------- convert ALL layers out_w (f32) -> obfAll (bf16, 4x1024x2048) -------
__global__ __launch_bounds__(256) void cvt4_k(const float* __restrict__ src,
                                              u16* __restrict__ dst) {
    int idx = (blockIdx.x * 256 + threadIdx.x) * 4;
    float4 v = *(const float4*)(src + idx);
    dst[idx + 0] = f2b(v.x); dst[idx + 1] = f2b(v.y);
    dst[idx + 2] = f2b(v.z); dst[idx + 3] = f2b(v.w);
}

// ---------------- bf16 GEMM (m97 structure): C[m,n] = sum_k A[m,k]*B[n,k] ---
// Used only as gemm_k<0,1> (in-proj, bf16 LDS-coalesced store) — proven form.
template <int EPI, int KSPLIT>
__global__ __launch_bounds__(256) void gemm_k(const u16* __restrict__ A,
                                              const u16* __restrict__ Bw,
                                              u16* __restrict__ Cb,
                                              float* __restrict__ Cf,
                                              int N, int Kd, int ldc) {
    __shared__ u16 sm[8192];          // As = sm[0:4096], Bs = sm[4096:8192]
    u16* As = sm;
    u16* Bs = sm + 4096;
    const int tid = threadIdx.x;
    const int lane = tid & 63;
    const int w = tid >> 6;
    const int wm = w >> 1, wn = w & 1;
    const int nb = N >> 7;

    const int rowsPer = (gridDim.x / nb) >> 3;
    const int xcd = blockIdx.x & 7;
    const int local = blockIdx.x >> 3;
    const int bx = local / rowsPer;
    const int by = xcd * rowsPer + (local % rowsPer);
    const int row0 = by << 7, col0 = bx << 7;

    const int Kslice = Kd / KSPLIT;
    const int kbase = blockIdx.y * Kslice;

    const int srow = lane >> 2;
    const int skp  = (lane & 3) << 3;

    f32x4 zero = {0.f, 0.f, 0.f, 0.f};
    f32x4 acc[4][4];
#pragma unroll
    for (int i = 0; i < 4; i++)
#pragma unroll
        for (int j = 0; j < 4; j++) acc[i][j] = zero;

    const int tiles = Kslice >> 5;
    for (int kt = 0; kt < tiles; ++kt) {
        const int k0 = kbase + (kt << 5);
#pragma unroll
        for (int j = 0; j < 2; ++j) {
            int r = w * 32 + j * 16 + srow;
            gload16(A + (size_t)(row0 + r) * Kd + k0 + skp,
                    As + w * 1024 + j * 512);
            gload16(Bw + (size_t)(col0 + r) * Kd + k0 + skp,
                    Bs + w * 1024 + j * 512);
        }
        __syncthreads();
        bf16x8 af[4], bfr[4];
#pragma unroll
        for (int mi = 0; mi < 4; mi++) {
            int row = wm * 64 + mi * 16 + (lane & 15);
            af[mi] = *(const bf16x8*)(As + row * 32 + ((lane >> 4) << 3));
        }
#pragma unroll
        for (int ni = 0; ni < 4; ni++) {
            int row = wn * 64 + ni * 16 + (lane & 15);
            bfr[ni] = *(const bf16x8*)(Bs + row * 32 + ((lane >> 4) << 3));
        }
#pragma unroll
        for (int mi = 0; mi < 4; mi++)
#pragma unroll
            for (int ni = 0; ni < 4; ni++)
                acc[mi][ni] = MFMA16(af[mi], bfr[ni], acc[mi][ni], 0, 0, 0);
        __syncthreads();
    }

    if (EPI == 0) {
#pragma unroll
        for (int half = 0; half < 2; ++half) {
            if (wm == half) {
#pragma unroll
                for (int mi = 0; mi < 4; mi++)
#pragma unroll
                    for (int ni = 0; ni < 4; ni++) {
                        int lr = mi * 16 + ((lane >> 4) << 2);
                        int col = wn * 64 + ni * 16 + (lane & 15);
#pragma unroll
                        for (int rr = 0; rr < 4; rr++)
                            sm[(lr + rr) * 128 + col] = f2b(acc[mi][ni][rr]);
                    }
            }
            __syncthreads();
#pragma unroll
            for (int q = 0; q < 4; q++) {
                int lr = w * 16 + q * 4 + (lane >> 4);
                int colb = (lane & 15) * 16;
                int4 v = *(const int4*)((const char*)sm + lr * 256 + colb);
                char* gp = (char*)(Cb + (size_t)(row0 + half * 64 + lr) * ldc + col0) + colb;
                *(int4*)gp = v;
            }
            __syncthreads();
        }
    } else {
#pragma unroll
        for (int mi = 0; mi < 4; mi++)
#pragma unroll
            for (int ni = 0; ni < 4; ni++) {
                int mbase = row0 + wm * 64 + mi * 16 + ((lane >> 4) << 2);
                int n = col0 + wn * 64 + ni * 16 + (lane & 15);
#pragma unroll
                for (int rr = 0; rr < 4; rr++) {
                    size_t off = (size_t)(mbase + rr) * ldc + n;
                    if (KSPLIT == 1) Cf[off] += acc[mi][ni][rr];
                    else atomicAdd(Cf + off, acc[mi][ni][rr]);
                }
            }
    }
}

// ---------------- out-proj GEMM: res[m,n] += sum_k y2[m,k]*obf[n,k] ---------
// 128x64 tile, 512 blocks, deterministic bf16 RMW (no atomics).
__global__ __launch_bounds__(256) void gemmo_k(const u16* __restrict__ A,
                                               const u16* __restrict__ Bw,
                                               u16* __restrict__ Cf) {
    __shared__ u16 As[128 * 32];      // 8 KB
    __shared__ u16 Bs[64 * 32];       // 4 KB
    const int tid = threadIdx.x;
    const int lane = tid & 63;
    const int w = tid >> 6;
    const int wm = w >> 1, wn = w & 1;

    const int rowsPer = 4;
    const int xcd = blockIdx.x & 7;
    const int local = blockIdx.x >> 3;
    const int bx = local / rowsPer;
    const int by = xcd * rowsPer + (local % rowsPer);
    const int row0 = by << 7, col0 = bx << 6;

    const int srow = lane >> 2;          // 0..15
    const int skp  = (lane & 3) << 3;    // 0,8,16,24

    f32x4 zero = {0.f, 0.f, 0.f, 0.f};
    f32x4 acc[4][2];
#pragma unroll
    for (int i = 0; i < 4; i++)
#pragma unroll
        for (int j = 0; j < 2; j++) acc[i][j] = zero;

    const int tiles = DI >> 5;           // 64
    for (int kt = 0; kt < tiles; ++kt) {
        const int k0 = kt << 5;
#pragma unroll
        for (int j = 0; j < 2; ++j) {
            int r = w * 32 + j * 16 + srow;
            gload16(A + (size_t)(row0 + r) * DI + k0 + skp,
                    As + w * 1024 + j * 512);
        }
        {
            int r = w * 16 + srow;
            gload16(Bw + (size_t)(col0 + r) * DI + k0 + skp,
                    Bs + w * 512);
        }
        __syncthreads();
        bf16x8 af[4], bfr[2];
#pragma unroll
        for (int mi = 0; mi < 4; mi++) {
            int row = wm * 64 + mi * 16 + (lane & 15);
            af[mi] = *(const bf16x8*)(As + row * 32 + ((lane >> 4) << 3));
        }
#pragma unroll
        for (int ni = 0; ni < 2; ni++) {
            int row = wn * 32 + ni * 16 + (lane & 15);
            bfr[ni] = *(const bf16x8*)(Bs + row * 32 + ((lane >> 4) << 3));
        }
#pragma unroll
        for (int mi = 0; mi < 4; mi++)
#pragma unroll
            for (int ni = 0; ni < 2; ni++)
                acc[mi][ni] = MFMA16(af[mi], bfr[ni], acc[mi][ni], 0, 0, 0);
        __syncthreads();
    }

#pragma unroll
    for (int mi = 0; mi < 4; mi++)
#pragma unroll
        for (int ni = 0; ni < 2; ni++) {
            int mbase = row0 + wm * 64 + mi * 16 + ((lane >> 4) << 2);
            int n = col0 + wn * 32 + ni * 16 + (lane & 15);
#pragma unroll
            for (int rr = 0; rr < 4; rr++) {
                size_t off = (size_t)(mbase + rr) * DM + n;
                Cf[off] = f2b(b2f(Cf[off]) + acc[mi][ni][rr]);
            }
        }
}

// ---------------- causal conv1d (K=4) + bias + SiLU, x4 vectorized ----------
// thread -> (t, 4-channel group); exact grid TOK*DCONV/4/256 = 8704 blocks
__global__ __launch_bounds__(256) void conv_k(const u16* __restrict__ zx,
                                              const float* __restrict__ cw,
                                              const float* __restrict__ cb,
                                              u16* __restrict__ xbc) {
    int idx = blockIdx.x * 256 + threadIdx.x;
    int c0 = (idx % (DCONV / 4)) * 4;
    int t  = idx / (DCONV / 4);
    int s = t % SEQ;
    float a0 = cb[c0 + 0], a1 = cb[c0 + 1], a2 = cb[c0 + 2], a3 = cb[c0 + 3];
    float4 w0 = *(const float4*)(cw + (c0 + 0) * KC);
    float4 w1 = *(const float4*)(cw + (c0 + 1) * KC);
    float4 w2 = *(const float4*)(cw + (c0 + 2) * KC);
    float4 w3 = *(const float4*)(cw + (c0 + 3) * KC);
#pragma unroll
    for (int k = 0; k < KC; k++) {
        int ss = s - 3 + k;
        if (ss >= 0) {
            ushort4 v = *(const ushort4*)(zx + (size_t)(t - 3 + k) * DINP + DI + c0);
            float tap0 = (k == 0) ? w0.x : (k == 1) ? w0.y : (k == 2) ? w0.z : w0.w;
            float tap1 = (k == 0) ? w1.x : (k == 1) ? w1.y : (k == 2) ? w1.z : w1.w;
            float tap2 = (k == 0) ? w2.x : (k == 1) ? w2.y : (k == 2) ? w2.z : w2.w;
            float tap3 = (k == 0) ? w3.x : (k == 1) ? w3.y : (k == 2) ? w3.z : w3.w;
            a0 += tap0 * b2f(v.x);
            a1 += tap1 * b2f(v.y);
            a2 += tap2 * b2f(v.z);
            a3 += tap3 * b2f(v.w);
        }
    }
    a0 = a0 / (1.f + __expf(-a0));
    a1 = a1 / (1.f + __expf(-a1));
    a2 = a2 / (1.f + __expf(-a2));
    a3 = a3 / (1.f + __expf(-a3));
    ushort4 o;
    o.x = f2b(a0); o.y = f2b(a1); o.z = f2b(a2); o.w = f2b(a3);
    *(ushort4*)(xbc + (size_t)t * DCONV + c0) = o;
}

// ---------------- dt/acum: LDS-staged parallel load + fast cumsum -----------
// block = b*NC + c ; 256 threads
__global__ __launch_bounds__(256) void dtacum_k(const u16* __restrict__ zx,
                                                const float* __restrict__ dtb,
                                                const float* __restrict__ alog,
                                                float* __restrict__ dt,
                                                float* __restrict__ acum) {
    __shared__ float raw[64][33], dts[64][33], acs[64][33];
    int bc = blockIdx.x;
    int t0 = bc * CHK;
    int tid = threadIdx.x;
#pragma unroll
    for (int it = 0; it < 8; ++it) {
        int idx = it * 256 + tid;
        int l = idx >> 5, h = idx & 31;
        raw[l][h] = b2f(zx[(size_t)(t0 + l) * DINP + DI + DCONV + h]);
    }
    __syncthreads();
    if (tid < NH) {
        int h = tid;
        float bias = dtb[h];
        float Ah = -__expf(alog[h]);
        float run = 0.f;
#pragma unroll 4
        for (int l = 0; l < CHK; l++) {
            float x = raw[l][h] + bias;
            float d = (x > 20.f) ? x : log1pf(__expf(x));
            dts[l][h] = d;
            run += d * Ah;
            acs[l][h] = run;
        }
    }
    __syncthreads();
#pragma unroll
    for (int it = 0; it < 8; ++it) {
        int idx = it * 256 + tid;
        int l = idx >> 5, h = idx & 31;
        dt[(size_t)(t0 + l) * NH + h] = dts[l][h];
        acum[(size_t)(t0 + l) * NH + h] = acs[l][h];
    }
}

// ---------------- intra-chunk via MFMA (exp-factorized), bf16 yb/st ---------
// block = (b*NC+c)*(NH/HPB) + hg ; heads h = hg*HPB + 0..HPB-1
__global__ __launch_bounds__(256) void ydiagm_k(const u16* __restrict__ xbc,
                                                const float* __restrict__ dt_,
                                                const float* __restrict__ acum,
                                                const float* __restrict__ Dw,
                                                u16* __restrict__ yb,
                                                u16* __restrict__ st) {
    __shared__ u16 Bl[8192/2], Cl[8192/2], BlT[8192/2], CBm[8192/2], XpT[8192/2];
    __shared__ float cs[2][64], rs[2][64];
    const int tid = threadIdx.x;
    const int lane = tid & 63;
    const int w = tid >> 6;
    const int blk = blockIdx.x;
    const int hg = blk & (NH / HPB - 1);
    const int bc = blk / (NH / HPB);
    const int t0 = bc * CHK;

    for (int it = 0; it < 8; ++it) {
        int idx2 = it * 256 + tid;
        int r = idx2 >> 5;
        int j0 = (idx2 & 31) * 2;
        size_t rowp = (size_t)(t0 + r) * DCONV;
        uint32_t bv = *(const uint32_t*)(xbc + rowp + DI + j0);
        uint32_t cv = *(const uint32_t*)(xbc + rowp + DI + DSTT + j0);
        st32(Bl, r, j0, bv);
        st32(Cl, r, j0, cv);
        st16(BlT, j0, r, (u16)(bv & 0xffff));
        st16(BlT, j0 + 1, r, (u16)(bv >> 16));
    }
    {
        int4 z4 = {0, 0, 0, 0};
        *(int4*)((char*)CBm + tid * 16) = z4;
        *(int4*)((char*)CBm + 4096 + tid * 16) = z4;
    }
    if (tid < 64) {
        int h0 = hg * HPB;
        float a = acum[(size_t)(t0 + tid) * NH + h0];
        float d = dt_[(size_t)(t0 + tid) * NH + h0];
        cs[0][tid] = __expf(-a) * d;
        rs[0][tid] = __expf(a);
    }
    __syncthreads();

    {
        bf16x8 a0 = ldfrag(Cl, w * 16, 0, lane);
        bf16x8 a1 = ldfrag(Cl, w * 16, 1, lane);
        for (int stt = 0; stt <= w; ++stt) {
            f32x4 acc = {0.f, 0.f, 0.f, 0.f};
            acc = MFMA16(a0, ldfrag(Bl, stt * 16, 0, lane), acc, 0, 0, 0);
            acc = MFMA16(a1, ldfrag(Bl, stt * 16, 1, lane), acc, 0, 0, 0);
            int lrow = w * 16 + ((lane >> 4) << 2);
            int scol = stt * 16 + (lane & 15);
#pragma unroll
            for (int rr = 0; rr < 4; rr++) {
                int lg = lrow + rr;
                u16 v = (scol <= lg) ? f2b(acc[rr]) : (u16)0;
                st16(CBm, lg, scol, v);
            }
        }
    }

    int cur = 0;
    for (int hh = 0; hh < HPB; ++hh) {
        const int h = hg * HPB + hh;
        const int nxt = cur ^ 1;
        for (int it = 0; it < 8; ++it) {
            int s0 = it * 8 + w * 2;
            float c0 = cs[cur][s0], c1 = cs[cur][s0 + 1];
            float x0 = b2f(xbc[(size_t)(t0 + s0) * DCONV + h * HP + lane]);
            float x1 = b2f(xbc[(size_t)(t0 + s0 + 1) * DCONV + h * HP + lane]);
            uint32_t pk = (uint32_t)f2b(c0 * x0) | ((uint32_t)f2b(c1 * x1) << 16);
            st32(XpT, lane, s0, pk);
        }
        if (hh < HPB - 1 && tid < 64) {
            float a = acum[(size_t)(t0 + tid) * NH + h + 1];
            float d = dt_[(size_t)(t0 + tid) * NH + h + 1];
            cs[nxt][tid] = __expf(-a) * d;
            rs[nxt][tid] = __expf(a);
        }
        __syncthreads();

        {
            float Dh = Dw[h];
#pragma unroll
            for (int nt = 0; nt < 4; ++nt) {
                f32x4 acc = {0.f, 0.f, 0.f, 0.f};
                acc = MFMA16(ldfrag(CBm, w * 16, 0, lane),
                             ldfrag(XpT, nt * 16, 0, lane), acc, 0, 0, 0);
                if (w >= 2)
                    acc = MFMA16(ldfrag(CBm, w * 16, 1, lane),
                                 ldfrag(XpT, nt * 16, 1, lane), acc, 0, 0, 0);
                int lrow = w * 16 + ((lane >> 4) << 2);
                int pg = nt * 16 + (lane & 15);
#pragma unroll
                for (int rr = 0; rr < 4; rr++) {
                    int lg = lrow + rr;
                    float xr = b2f(xbc[(size_t)(t0 + lg) * DCONV + h * HP + pg]);
                    yb[(size_t)(t0 + lg) * DI + h * HP + pg] =
                        f2b(rs[cur][lg] * acc[rr] + Dh * xr);
                }
            }
        }
        {
            float dcv = rs[cur][63];
            u16* so = st + (size_t)(bc * NH + h) * (HP * DSTT);
            bf16x8 a0 = ldfrag(XpT, w * 16, 0, lane);
            bf16x8 a1 = ldfrag(XpT, w * 16, 1, lane);
#pragma unroll
            for (int nt = 0; nt < 4; ++nt) {
                f32x4 acc = {0.f, 0.f, 0.f, 0.f};
                acc = MFMA16(a0, ldfrag(BlT, nt * 16, 0, lane), acc, 0, 0, 0);
                acc = MFMA16(a1, ldfrag(BlT, nt * 16, 1, lane), acc, 0, 0, 0);
                int prow = w * 16 + ((lane >> 4) << 2);
                int ng = nt * 16 + (lane & 15);
#pragma unroll
                for (int rr = 0; rr < 4; rr++)
                    so[(size_t)(prow + rr) * DSTT + ng] = f2b(dcv * acc[rr]);
            }
        }
        __syncthreads();
        cur ^= 1;
    }
}

// ---------------- element-parallel inter-chunk scan (in place, bf16) --------
__global__ __launch_bounds__(256) void chainscan_k(const float* __restrict__ acum,
                                                   u16* __restrict__ st) {
    __shared__ float dc[NC];
    int blk = blockIdx.x;
    int slice = blk & 15;
    int bh = blk >> 4;
    int h = bh % NH, b = bh / NH;
    int tid = threadIdx.x;
    if (tid < NC)
        dc[tid] = __expf(acum[(size_t)(b * SEQ + tid * CHK + CHK - 1) * NH + h]);
    __syncthreads();
    int e = slice * 256 + tid;
    u16* p = st + ((size_t)(b * NC) * NH + h) * (HP * DSTT) + e;
    const size_t cstride = (size_t)NH * HP * DSTT;
    float s = 0.f;
#pragma unroll 4
    for (int c = 0; c < NC; c++) {
        float v = b2f(p[c * cstride]);
        p[c * cstride] = f2b(s);
        s = dc[c] * s + v;
    }
}

// ---------------- y_off via MFMA: yb[l,p] += ea[l]*sum_n C[l,n]*S[p,n] ------
// block = (b*NC + c)*NH + h ; bf16 yb RMW, bf16 S (direct copy to LDS)
__global__ __launch_bounds__(256) void yoffm_k(const u16* __restrict__ xbc,
                                               const float* __restrict__ acum,
                                               const u16* __restrict__ S,
                                               u16* __restrict__ yb) {
    __shared__ u16 Cl[4096], Sl[4096];   // two 64x64 bf16 tiles
    __shared__ float eal[64];
    const int blk = blockIdx.x;
    const int h = blk % NH;
    const int bc = blk / NH;
    const int t0 = bc * CHK;
    const int tid = threadIdx.x;
    const int lane = tid & 63;
    const int w = tid >> 6;

    for (int it = 0; it < 8; ++it) {
        int idx2 = it * 256 + tid;
        int r = idx2 >> 5;              // 0..63
        int j0 = (idx2 & 31) * 2;       // 0..62 even
        uint32_t cv = *(const uint32_t*)(xbc + (size_t)(t0 + r) * DCONV + DI + DSTT + j0);
        st32(Cl, r, j0, cv);
    }
    const u16* Sp = S + (size_t)blk * (HP * DSTT);
    for (int it = 0; it < 8; ++it) {
        int idx2 = it * 256 + tid;
        int p = idx2 >> 5;
        int j0 = (idx2 & 31) * 2;
        uint32_t sv = *(const uint32_t*)(Sp + p * DSTT + j0);
        st32(Sl, p, j0, sv);
    }
    if (tid < 64) eal[tid] = __expf(acum[(size_t)(t0 + tid) * NH + h]);
    __syncthreads();

    bf16x8 a0 = ldfrag(Cl, w * 16, 0, lane);
    bf16x8 a1 = ldfrag(Cl, w * 16, 1, lane);
#pragma unroll
    for (int nt = 0; nt < 4; ++nt) {
        f32x4 acc = {0.f, 0.f, 0.f, 0.f};
        acc = MFMA16(a0, ldfrag(Sl, nt * 16, 0, lane), acc, 0, 0, 0);
        acc = MFMA16(a1, ldfrag(Sl, nt * 16, 1, lane), acc, 0, 0, 0);
        int lrow = w * 16 + ((lane >> 4) << 2);
        int pg = nt * 16 + (lane & 15);
#pragma unroll
        for (int rr = 0; rr < 4; rr++) {
            int lg = lrow + rr;
            u16* yp = yb + (size_t)(t0 + lg) * DI + h * HP + pg;
            *yp = f2b(b2f(*yp) + eal[lg] * acc[rr]);
        }
    }
}

// ---------------- gate (y * silu(z)) + RMSNorm * rms_w -> bf16 --------------
__global__ __launch_bounds__(256) void gaterms_k(const u16* __restrict__ yb,
                                                 const u16* __restrict__ zx,
                                                 const float* __restrict__ rw,
                                                 u16* __restrict__ y2) {
    __shared__ float red[4];
    int t = blockIdx.x, tid = threadIdx.x;
    const u16* yr = yb + (size_t)t * DI;
    const u16* zr = zx + (size_t)t * DINP;
    int i0 = tid * 8;
    int4 yv4 = *(const int4*)(yr + i0);
    int4 zv4 = *(const int4*)(zr + i0);
    const u16* yp = (const u16*)&yv4;
    const u16* zp = (const u16*)&zv4;
    float g[8];
    float ss = 0.f;
#pragma unroll
    for (int j = 0; j < 8; j++) {
        float y = b2f(yp[j]);
        float z = b2f(zp[j]);
        float sl = z / (1.f + __expf(-z));
        float v = y * sl;
        g[j] = v;
        ss += v * v;
    }
#pragma unroll
    for (int off = 32; off; off >>= 1) ss += __shfl_down(ss, off);
    if ((tid & 63) == 0) red[tid >> 6] = ss;
    __syncthreads();
    float tot = red[0] + red[1] + red[2] + red[3];
    float sc = rsqrtf(tot * (1.f / DI) + 1e-5f);
    u16* yo = y2 + (size_t)t * DI + i0;
#pragma unroll
    for (int j = 0; j < 8; j++) yo[j] = f2b(g[j] * sc * rw[i0 + j]);
}

// ============================ host-side launch ==============================
extern "C" void kernel_launch(void* const* d_in, const int* in_sizes, int n_in,
                              void* d_out, int out_size, void* d_ws, size_t ws_size,
                              hipStream_t stream) {
    const int*   ids      = (const int*)d_in[0];
    const float* emb      = (const float*)d_in[2];
    const float* ln_w     = (const float*)d_in[3];
    const float* ln_b     = (const float*)d_in[4];
    const float* in_w     = (const float*)d_in[5];
    const float* conv_w   = (const float*)d_in[6];
    const float* conv_b   = (const float*)d_in[7];
    const float* dt_bias  = (const float*)d_in[8];
    const float* A_log    = (const float*)d_in[9];
    const float* Dw       = (const float*)d_in[10];
    const float* rms_w    = (const float*)d_in[11];
    const float* out_w    = (const float*)d_in[12];
    const float* norm_w   = (const float*)d_in[13];
    const float* norm_b   = (const float*)d_in[14];

    char* ws = (char*)d_ws;
    u16*   res    = (u16*)  (ws);                  //  8,388,608 B (bf16 now)
    u16*   zx     = (u16*)  (ws + 16777216);       // 35,651,584 B (stride DINP)
    u16*   xbc    = (u16*)  (ws + 52428800);       // 17,825,792 B
    float* dt     = (float*)(ws + 70254592);       //    524,288 B
    float* acum   = (float*)(ws + 70778880);       //    524,288 B
    u16*   yb     = (u16*)  (ws + 71303168);       // 16,777,216 B (bf16)
    u16*   h      = (u16*)  (ws + 88080384);       //  8,388,608 B
    u16*   st     = (u16*)  (ws + 104857600);      // 16,777,216 B (bf16)
    u16*   y2     = (u16*)  (ws + 138412032);      // 16,777,216 B
    u16*   wpadAll= (u16*)  (ws + 155189248);      // 35,651,584 B (4 layers)
    u16*   obfAll = (u16*)  (ws + 190840832);      // 16,777,216 B (4 layers)
    const size_t NEED = 207618048;
    if (ws_size < NEED) return;

    // one-shot weight conversions (all layers)
    padw4_k<<<NLAY * DINP * DM / 4 / 256, 256, 0, stream>>>(in_w, wpadAll);
    cvt4_k<<<NLAY * DM * DI / 4 / 256, 256, 0, stream>>>(out_w, obfAll);

    embed_k<<<TOK, 256, 0, stream>>>(ids, emb, res);

    for (int l = 0; l < NLAY; ++l) {
        ln_k<u16><<<TOK, 256, 0, stream>>>(res, ln_w + l * DM, ln_b + l * DM, h);
        gemm_k<0, 1><<<(TOK / 128) * (DINP / 128), 256, 0, stream>>>(
            h, wpadAll + (size_t)l * DINP * DM, zx, nullptr, DINP, DM, DINP);
        conv_k<<<TOK * DCONV / 4 / 256, 256, 0, stream>>>(
            zx, conv_w + (size_t)l * DCONV * KC, conv_b + (size_t)l * DCONV, xbc);
        dtacum_k<<<BATCH * NC, 256, 0, stream>>>(
            zx, dt_bias + l * NH, A_log + l * NH, dt, acum);
        ydiagm_k<<<BATCH * NC * (NH / HPB), 256, 0, stream>>>(
            xbc, dt, acum, Dw + l * NH, yb, st);
        chainscan_k<<<BATCH * NH * 16, 256, 0, stream>>>(acum, st);
        yoffm_k<<<BATCH * NC * NH, 256, 0, stream>>>(xbc, acum, st, yb);
        gaterms_k<<<TOK, 256, 0, stream>>>(yb, zx, rms_w + (size_t)l * DI, y2);
        gemmo_k<<<512, 256, 0, stream>>>(
            y2, obfAll + (size_t)l * DM * DI, res);
    }

    ln_k<float><<<TOK, 256, 0, stream>>>(res, norm_w, norm_b, (float*)d_out);
}